// Round 1
// 2360.744 us; speedup vs baseline: 1.1064x; 1.1064x over previous
//
#include <hip/hip_runtime.h>
#include <cstdint>
#include <cstddef>

typedef __bf16 bf16;
typedef bf16 bf16x8 __attribute__((ext_vector_type(8)));
typedef float f32x4 __attribute__((ext_vector_type(4)));

#define GAS __attribute__((address_space(1)))
#define LAS __attribute__((address_space(3)))

__device__ __forceinline__ void async_cp16(const bf16* g, bf16* l) {
  __builtin_amdgcn_global_load_lds((const GAS unsigned int*)g,
                                   (LAS unsigned int*)l, 16, 0, 0);
}

__device__ __forceinline__ float gelu_f(float x) {
  return 0.5f * x * (1.0f + erff(x * 0.70710678118654752440f));
}

// ---------------- weight conversion ----------------
__global__ void __launch_bounds__(256) f2b_kernel(const float* __restrict__ in,
                                                  bf16* __restrict__ out, int n) {
  int i = (blockIdx.x * 256 + threadIdx.x) * 4;
  if (i >= n) return;
  float4 v = *(const float4*)&in[i];
  union { uint2 u; bf16 e[4]; } o;
  o.e[0] = (bf16)v.x; o.e[1] = (bf16)v.y; o.e[2] = (bf16)v.z; o.e[3] = (bf16)v.w;
  *(uint2*)&out[i] = o.u;
}

__global__ void __launch_bounds__(256) split3_kernel(const float* __restrict__ in,
    bf16* __restrict__ oh, bf16* __restrict__ om, bf16* __restrict__ ol, int n) {
  int i = (blockIdx.x * 256 + threadIdx.x) * 4;
  if (i >= n) return;
  float4 v = *(const float4*)&in[i];
  float a[4] = {v.x, v.y, v.z, v.w};
  union { uint2 u; bf16 e[4]; } h, m, l;
#pragma unroll
  for (int j = 0; j < 4; j++) {
    h.e[j] = (bf16)a[j];
    float r = a[j] - (float)h.e[j];
    m.e[j] = (bf16)r;
    l.e[j] = (bf16)(r - (float)m.e[j]);
  }
  *(uint2*)&oh[i] = h.u;
  *(uint2*)&om[i] = m.u;
  *(uint2*)&ol[i] = l.u;
}

// ---------------- layernorm (full M; optional 3-way split) ----------------
template<int SPLIT>
__global__ void __launch_bounds__(256) ln_kernel(const float* __restrict__ X,
    const float* __restrict__ w, const float* __restrict__ b,
    bf16* __restrict__ oh, bf16* __restrict__ om, bf16* __restrict__ ol) {
  const int row = blockIdx.x;
  const int tid = threadIdx.x;
  const float4 xv = *(const float4*)&X[(size_t)row * 1024 + tid * 4];
  float s1 = xv.x + xv.y + xv.z + xv.w;
  float s2 = xv.x * xv.x + xv.y * xv.y + xv.z * xv.z + xv.w * xv.w;
#pragma unroll
  for (int d = 1; d < 64; d <<= 1) {
    s1 += __shfl_xor(s1, d, 64);
    s2 += __shfl_xor(s2, d, 64);
  }
  __shared__ float red[8];
  if ((tid & 63) == 0) { red[tid >> 6] = s1; red[4 + (tid >> 6)] = s2; }
  __syncthreads();
  s1 = red[0] + red[1] + red[2] + red[3];
  s2 = red[4] + red[5] + red[6] + red[7];
  const float mu = s1 * (1.0f / 1024.0f);
  const float var = s2 * (1.0f / 1024.0f) - mu * mu;
  const float rs = rsqrtf(var + 1e-5f);
  const float4 wv = *(const float4*)&w[tid * 4];
  const float4 bv = *(const float4*)&b[tid * 4];
  float y[4] = {(xv.x - mu) * rs * wv.x + bv.x,
                (xv.y - mu) * rs * wv.y + bv.y,
                (xv.z - mu) * rs * wv.z + bv.z,
                (xv.w - mu) * rs * wv.w + bv.w};
  union { uint2 u; bf16 e[4]; } h;
#pragma unroll
  for (int j = 0; j < 4; j++) h.e[j] = (bf16)y[j];
  *(uint2*)&oh[(size_t)row * 1024 + tid * 4] = h.u;
  if (SPLIT == 3) {
    union { uint2 u; bf16 e[4]; } m, l;
#pragma unroll
    for (int j = 0; j < 4; j++) {
      float r = y[j] - (float)h.e[j];
      m.e[j] = (bf16)r;
      l.e[j] = (bf16)(r - (float)m.e[j]);
    }
    *(uint2*)&om[(size_t)row * 1024 + tid * 4] = m.u;
    *(uint2*)&ol[(size_t)row * 1024 + tid * 4] = l.u;
  }
}

// ---------------- layernorm on compacted rows, zero-fill to 128-pad ----------------
__global__ void __launch_bounds__(256) ln_c_kernel(const float* __restrict__ X,
    const float* __restrict__ w, const float* __restrict__ b,
    bf16* __restrict__ oh, const int* __restrict__ cnt_ptr) {
  const int row = blockIdx.x;
  const int cnt = *cnt_ptr;
  const int pad = (cnt + 127) & ~127;
  if (row >= pad) return;
  const int tid = threadIdx.x;
  if (row >= cnt) {
    *(uint2*)&oh[(size_t)row * 1024 + tid * 4] = make_uint2(0, 0);
    return;
  }
  const float4 xv = *(const float4*)&X[(size_t)row * 1024 + tid * 4];
  float s1 = xv.x + xv.y + xv.z + xv.w;
  float s2 = xv.x * xv.x + xv.y * xv.y + xv.z * xv.z + xv.w * xv.w;
#pragma unroll
  for (int d = 1; d < 64; d <<= 1) {
    s1 += __shfl_xor(s1, d, 64);
    s2 += __shfl_xor(s2, d, 64);
  }
  __shared__ float red[8];
  if ((tid & 63) == 0) { red[tid >> 6] = s1; red[4 + (tid >> 6)] = s2; }
  __syncthreads();
  s1 = red[0] + red[1] + red[2] + red[3];
  s2 = red[4] + red[5] + red[6] + red[7];
  const float mu = s1 * (1.0f / 1024.0f);
  const float var = s2 * (1.0f / 1024.0f) - mu * mu;
  const float rs = rsqrtf(var + 1e-5f);
  const float4 wv = *(const float4*)&w[tid * 4];
  const float4 bv = *(const float4*)&b[tid * 4];
  union { uint2 u; bf16 e[4]; } h;
  h.e[0] = (bf16)((xv.x - mu) * rs * wv.x + bv.x);
  h.e[1] = (bf16)((xv.y - mu) * rs * wv.y + bv.y);
  h.e[2] = (bf16)((xv.z - mu) * rs * wv.z + bv.z);
  h.e[3] = (bf16)((xv.w - mu) * rs * wv.w + bv.w);
  *(uint2*)&oh[(size_t)row * 1024 + tid * 4] = h.u;
}

// ---------------- depth-compaction index build ----------------
__global__ void zero_cnt_kernel(int* cnt_all, int* bcnt_all) {
  if (threadIdx.x < 6) cnt_all[threadIdx.x] = 0;
  if (threadIdx.x < 48) bcnt_all[threadIdx.x] = 0;
}

__global__ void __launch_bounds__(256) build_idx_kernel(
    const int* __restrict__ gate, int* __restrict__ idx_all,
    int* __restrict__ cnt_all, int* __restrict__ bidx_all,
    int* __restrict__ bcnt_all) {
  const int lev = blockIdx.x >> 3;   // 0..5
  const int b   = blockIdx.x & 7;
  const int level = lev + 1;
  int* idx  = idx_all + lev * 8192;
  int* bidx = bidx_all + lev * 8192 + b * 1024;
  for (int t = threadIdx.x; t < 1024; t += 256) {
    const int row = b * 1024 + t;
    if (gate[row] >= level) {
      int p = atomicAdd(&bcnt_all[lev * 8 + b], 1);
      bidx[p] = t;
      int q = atomicAdd(&cnt_all[lev], 1);
      idx[q] = row;
    }
  }
}

// XCD-aware block remap (128-tile version, used by gemm_router).
__device__ __forceinline__ void swizzle_mn(int gx, int& m0, int& n0) {
  const int id = blockIdx.y * gx + blockIdx.x;
  const int k8 = id & 7, t = id >> 3;
  n0 = (t % gx) * 128;
  m0 = ((t / gx) * 8 + k8) * 128;
}

// ================= 256-row-tile 8-wave 4-phase pipelined NT GEMM =================
// BM = 256 always. BN = 256 (waves 2x4, per-wave 128x64) or 128 (waves 4x2,
// per-wave 64x64). BK = 64, double-buffered LDS (A: 2 halves of 128x64, B: NBH
// halves), LDS XOR-swizzle (slot ^= row&7 on 16B chunks of the 128B row) applied
// on the global staging source AND the ds_read address (LDS dest stays linear for
// global_load_lds). Schedule per K-tile t (buf = t&1), 4 phases:
//   p: { ds_read A-frags for this phase (+ all B-frags at p0);
//        stage one half-tile [p0: A-lo(t+1)->buf^1, p1: A-hi(t+1)->buf^1,
//                             p2: B-lo(t+2)->buf,  p3: B-hi(t+2)->buf];
//        s_barrier; lgkmcnt(0); setprio(1); 16 (or 8) MFMA; setprio(0);
//        [p3: s_waitcnt vmcnt(4|2), never 0 in steady state]; s_barrier }
// Lifetimes: B(t) fully read in p0 (all waves, enforced by p0's closing barrier)
// so B(t+2) may land from p2; A(t) fully read at end of p3 so A(t+1) goes to the
// other buffer. Boundary vmcnt(4) leaves exactly B(t+2)'s 4 loads in flight.
// MODE semantics identical to the old gemm_nt (0..4).
template<int MODE, int BN>
__global__ void __launch_bounds__(512, 2) gemm256(
    const bf16* __restrict__ A, const bf16* __restrict__ B,
    const float* __restrict__ bias, const float* __restrict__ Res,
    float* __restrict__ C32, bf16* __restrict__ Cb,
    const int* __restrict__ idx, const int* __restrict__ cnt_ptr,
    int N, int K, int ldc, int coff) {
  __shared__ bf16 lds[65536];   // 128 KiB: A halves [0,32768), B halves [32768,65536)
  const int tid = threadIdx.x;
  const int w = tid >> 6, lane = tid & 63;
  const int lr = lane & 15, lq = lane >> 4;
  constexpr int MI  = (BN == 256) ? 8 : 4;   // A frags per wave
  constexpr int MPH = (BN == 256) ? 2 : 1;   // A frags per phase
  constexpr int NBH = (BN == 256) ? 2 : 1;   // B half-tiles
  const int wr = (BN == 256) ? (w >> 2) : (w >> 1);
  const int wc = (BN == 256) ? (w & 3) : (w & 1);

  // XCD-aware tile coords (grid.x * grid.y is a multiple of 8 in all call sites)
  const int gx = gridDim.x;
  const int id = blockIdx.y * gx + blockIdx.x;
  const int k8 = id & 7, tt = id >> 3;
  const int n0 = (tt % gx) * BN;
  const int m0 = ((tt / gx) * 8 + k8) * 256;

  int cnt = 0x7fffffff;
  if (MODE != 0) {
    cnt = *cnt_ptr;
    if (m0 >= cnt) return;
  }

  const int NT = K >> 6;

  // ---- staging source pointers (per-thread, swizzled k-chunk) ----
  const int srow  = tid >> 3;                       // 0..63
  const int skoff = ((tid & 7) ^ (srow & 7)) * 8;   // LDS[row][slot]=G[row][slot^(row&7)]
  const bf16* gA[4];
#pragma unroll
  for (int h = 0; h < 2; h++)
#pragma unroll
    for (int j = 0; j < 2; j++) {
      const int i = m0 + h * 128 + j * 64 + srow;
      size_t ar;
      if (MODE == 1 || MODE == 2) ar = (size_t)idx[i < cnt ? i : 0];
      else ar = (size_t)i;
      gA[h * 2 + j] = A + ar * (size_t)K + skoff;
    }
  const bf16* gB[4];
#pragma unroll
  for (int h = 0; h < NBH; h++)
#pragma unroll
    for (int j = 0; j < 2; j++)
      gB[h * 2 + j] = B + (size_t)(n0 + h * 128 + j * 64 + srow) * K + skoff;

  auto stageA = [&](int bf, int h, int t) {
#pragma unroll
    for (int j = 0; j < 2; j++)
      async_cp16(gA[h * 2 + j] + (size_t)t * 64,
                 &lds[(bf * 2 + h) * 8192 + (j * 64 + w * 8) * 64]);
  };
  auto stageB = [&](int bf, int h, int t) {
#pragma unroll
    for (int j = 0; j < 2; j++)
      async_cp16(gB[h * 2 + j] + (size_t)t * 64,
                 &lds[32768 + (bf * 2 + h) * 8192 + (j * 64 + w * 8) * 64]);
  };

  // ---- fragment read helpers (swizzled) ----
  const int ah  = (BN == 256) ? wr : (wr >> 1);          // A half for this wave
  const int arb = (BN == 256) ? 0 : ((wr & 1) * 64);     // row base within half
  const int bh  = (BN == 256) ? (wc >> 1) : 0;
  const int brb = (BN == 256) ? ((wc & 1) * 64) : (wc * 64);
  const int swz = (lr & 7);
  auto rdA = [&](int bf, int mi, int ks) {
    return *(const bf16x8*)&lds[(bf * 2 + ah) * 8192 + (arb + mi * 16 + lr) * 64
                                + (((ks * 4 + lq) ^ swz) * 8)];
  };
  auto rdB = [&](int bf, int ni, int ks) {
    return *(const bf16x8*)&lds[32768 + (bf * 2 + bh) * 8192
                                + (brb + ni * 16 + lr) * 64
                                + (((ks * 4 + lq) ^ swz) * 8)];
  };

  f32x4 acc[MI][4] = {};
  bf16x8 bq[4][2];

  // ---- prologue: tile0 fully + B(1); A(1) is staged inside t=0 ----
  stageA(0, 0, 0); stageA(0, 1, 0);
  stageB(0, 0, 0);
  if (BN == 256) stageB(0, 1, 0);
  stageB(1, 0, 1);
  if (BN == 256) stageB(1, 1, 1);
  asm volatile("s_waitcnt vmcnt(0)" ::: "memory");
  __builtin_amdgcn_s_barrier();

  for (int t = 0; t < NT; ++t) {
    const int bf = t & 1;
#pragma unroll
    for (int p = 0; p < 4; ++p) {
      bf16x8 af[2 * MPH];
#pragma unroll
      for (int m = 0; m < MPH; m++)
#pragma unroll
        for (int ks = 0; ks < 2; ks++)
          af[m * 2 + ks] = rdA(bf, p * MPH + m, ks);
      if (p == 0) {
#pragma unroll
        for (int ni = 0; ni < 4; ni++)
#pragma unroll
          for (int ks = 0; ks < 2; ks++)
            bq[ni][ks] = rdB(bf, ni, ks);
      }
      // one half-tile stage per phase
      if (p == 0)      { if (t + 1 < NT) stageA(bf ^ 1, 0, t + 1); }
      else if (p == 1) { if (t + 1 < NT) stageA(bf ^ 1, 1, t + 1); }
      else if (p == 2) { if (t + 2 < NT) stageB(bf, 0, t + 2); }
      else if (BN == 256) { if (t + 2 < NT) stageB(bf, 1, t + 2); }

      __builtin_amdgcn_s_barrier();
      asm volatile("s_waitcnt lgkmcnt(0)" ::: "memory");
      __builtin_amdgcn_sched_barrier(0);
      __builtin_amdgcn_s_setprio(1);
#pragma unroll
      for (int m = 0; m < MPH; m++) {
        const int mi = p * MPH + m;
#pragma unroll
        for (int ni = 0; ni < 4; ni++) {
          acc[mi][ni] = __builtin_amdgcn_mfma_f32_16x16x32_bf16(
              af[m * 2 + 0], bq[ni][0], acc[mi][ni], 0, 0, 0);
          acc[mi][ni] = __builtin_amdgcn_mfma_f32_16x16x32_bf16(
              af[m * 2 + 1], bq[ni][1], acc[mi][ni], 0, 0, 0);
        }
      }
      __builtin_amdgcn_s_setprio(0);
      __builtin_amdgcn_sched_barrier(0);
      if (p == 3) {
        if (t + 2 < NT) {
          if constexpr (BN == 256) asm volatile("s_waitcnt vmcnt(4)" ::: "memory");
          else                     asm volatile("s_waitcnt vmcnt(2)" ::: "memory");
        } else {
          asm volatile("s_waitcnt vmcnt(0)" ::: "memory");
        }
      }
      __builtin_amdgcn_s_barrier();
    }
  }

  // ---- epilogue (same semantics as old gemm_nt) ----
  const int rw = m0 + ((BN == 256) ? wr * 128 : wr * 64);
#pragma unroll
  for (int mi = 0; mi < MI; mi++) {
    const int rbase = rw + mi * 16 + lq * 4;
    int orig[4];
#pragma unroll
    for (int r = 0; r < 4; r++) {
      const int i = rbase + r;
      if (MODE == 1 || MODE == 2 || MODE == 4) orig[r] = (i < cnt) ? idx[i] : -1;
      else orig[r] = i;
    }
#pragma unroll
    for (int ni = 0; ni < 4; ni++) {
      const int c = n0 + wc * 64 + ni * 16 + lr;
      const float bv = bias[c];
#pragma unroll
      for (int r = 0; r < 4; r++) {
        const float v = acc[mi][ni][r] + bv;
        const int i = rbase + r;
        if (MODE == 0) {
          Cb[(size_t)i * ldc + coff + c] = (bf16)v;
        } else if (MODE == 1) {
          if (orig[r] >= 0) Cb[(size_t)orig[r] * ldc + c] = (bf16)v;
        } else if (MODE == 2) {
          const float rv = (orig[r] >= 0) ? Res[(size_t)orig[r] * N + c] : 0.0f;
          C32[(size_t)i * N + c] = rv + v;
        } else if (MODE == 3) {
          Cb[(size_t)i * N + c] = (bf16)gelu_f(v);
        } else {
          if (orig[r] >= 0)
            C32[(size_t)orig[r] * N + c] = Res[(size_t)i * N + c] + v;
        }
      }
    }
  }
}

// ---------------- fused 6-product split-bf16 router GEMM ----------------
__global__ void __launch_bounds__(256) gemm_router(
    const bf16* __restrict__ Ah, const bf16* __restrict__ Am, const bf16* __restrict__ Al,
    const bf16* __restrict__ Bh, const bf16* __restrict__ Bm, const bf16* __restrict__ Bl,
    float* __restrict__ C32) {
  __shared__ bf16 As[3][128 * 32];
  __shared__ bf16 Bs[3][128 * 32];
  const int tid = threadIdx.x;
  const int w = tid >> 6, lane = tid & 63;
  const int lr = lane & 15, lq = lane >> 4;
  int m0, n0;
  swizzle_mn(gridDim.x, m0, n0);
  const int wm = (w >> 1) * 64, wn = (w & 1) * 64;
  const int K = 1024;

  f32x4 acc[4][4] = {};

  const size_t aoff = (size_t)(m0 + (tid >> 2)) * K + (tid & 3) * 8;
  const size_t boff = (size_t)(n0 + (tid >> 2)) * K + (tid & 3) * 8;
  const bf16* gA[3] = {Ah + aoff, Am + aoff, Al + aoff};
  const bf16* gB[3] = {Bh + boff, Bm + boff, Bl + boff};
  const int lo = w * 512;
  const size_t step64 = (size_t)64 * K;

  const int cA[6] = {0, 0, 1, 1, 0, 2};
  const int cB[6] = {0, 1, 0, 1, 2, 0};

  for (int k0 = 0; k0 < K; k0 += 32) {
    __syncthreads();
#pragma unroll
    for (int j = 0; j < 3; j++) {
      async_cp16(gA[j] + k0, As[j] + lo);
      async_cp16(gA[j] + step64 + k0, As[j] + lo + 2048);
      async_cp16(gB[j] + k0, Bs[j] + lo);
      async_cp16(gB[j] + step64 + k0, Bs[j] + lo + 2048);
    }
    __syncthreads();
#pragma unroll
    for (int c = 0; c < 6; c++) {
      bf16x8 af[4], bfr[4];
#pragma unroll
      for (int i = 0; i < 4; i++)
        af[i] = *(const bf16x8*)&As[cA[c]][(wm + i * 16 + lr) * 32 + lq * 8];
#pragma unroll
      for (int i = 0; i < 4; i++)
        bfr[i] = *(const bf16x8*)&Bs[cB[c]][(wn + i * 16 + lr) * 32 + lq * 8];
#pragma unroll
      for (int mi = 0; mi < 4; mi++)
#pragma unroll
        for (int ni = 0; ni < 4; ni++)
          acc[mi][ni] = __builtin_amdgcn_mfma_f32_16x16x32_bf16(
              af[mi], bfr[ni], acc[mi][ni], 0, 0, 0);
    }
  }

#pragma unroll
  for (int mi = 0; mi < 4; mi++) {
    const int rbase = m0 + wm + mi * 16 + lq * 4;
#pragma unroll
    for (int ni = 0; ni < 4; ni++) {
      const int c = n0 + wn + ni * 16 + lr;
#pragma unroll
      for (int r = 0; r < 4; r++)
        C32[(size_t)(rbase + r) * 1024 + c] = acc[mi][ni][r];
    }
  }
}

// ---------------- router tail ----------------
__global__ void __launch_bounds__(256) gelu_bias_kernel(float* __restrict__ t,
    const float* __restrict__ bias, int n) {
  int i = (blockIdx.x * 256 + threadIdx.x) * 4;
  if (i >= n) return;
  float4 v = *(const float4*)&t[i];
  float4 bb = *(const float4*)&bias[i & 1023];
  v.x = gelu_f(v.x + bb.x);
  v.y = gelu_f(v.y + bb.y);
  v.z = gelu_f(v.z + bb.z);
  v.w = gelu_f(v.w + bb.w);
  *(float4*)&t[i] = v;
}

__global__ void __launch_bounds__(256) router_logits(const float* __restrict__ h,
    const float* __restrict__ w2, const float* __restrict__ b2,
    float* __restrict__ logits_out, float* __restrict__ depths_out,
    int* __restrict__ gate) {
  const int row = blockIdx.x * 4 + (threadIdx.x >> 6);
  const int lane = threadIdx.x & 63;
  const float* hr = h + (size_t)row * 1024;
  float part[6] = {0, 0, 0, 0, 0, 0};
  for (int kc = lane; kc < 256; kc += 64) {
    float4 hv = *(const float4*)&hr[kc * 4];
#pragma unroll
    for (int j = 0; j < 6; j++) {
      float4 wv = *(const float4*)&w2[j * 1024 + kc * 4];
      part[j] += hv.x * wv.x + hv.y * wv.y + hv.z * wv.z + hv.w * wv.w;
    }
  }
#pragma unroll
  for (int j = 0; j < 6; j++)
#pragma unroll
    for (int d = 1; d < 64; d <<= 1) part[j] += __shfl_xor(part[j], d, 64);
  if (lane == 0) {
    float best = -1e30f;
    int bi = 0;
#pragma unroll
    for (int j = 0; j < 6; j++) {
      const float v = part[j] + b2[j];
      logits_out[(size_t)row * 6 + j] = v;
      if (v > best) { best = v; bi = j; }
    }
    depths_out[row] = (float)(bi + 1);
    gate[row] = bi + 1;
  }
}

// ---------------- V transpose ----------------
__global__ void __launch_bounds__(256) vtrans_kernel(const bf16* __restrict__ qkv,
                                                     bf16* __restrict__ vt) {
  __shared__ bf16 T[64 * 64];
  const int tid = threadIdx.x;
  const int tb = blockIdx.x & 15, bh = blockIdx.x >> 4;
  const int b = bh >> 4, h = bh & 15;
#pragma unroll
  for (int i = 0; i < 2; i++) {
    const int c = tid + i * 256;
    const int tok = c >> 3, hd8 = (c & 7) * 8;
    uint4 v = *(const uint4*)&qkv[((size_t)b * 1024 + tb * 64 + tok) * 3072 + 2048 + h * 64 + hd8];
    *(uint4*)&T[tok * 64 + (hd8 ^ ((tok & 7) << 3))] = v;
  }
  __syncthreads();
#pragma unroll
  for (int i = 0; i < 2; i++) {
    const int c = tid + i * 256;
    const int hd = c >> 3, t8 = (c & 7) * 8;
    union { uint4 u; bf16 e[8]; } o;
#pragma unroll
    for (int j = 0; j < 8; j++)
      o.e[j] = T[(t8 + j) * 64 + (hd ^ (j << 3))];
    *(uint4*)&vt[((size_t)bh * 64 + hd) * 1024 + tb * 64 + t8] = o.u;
  }
}

// ---------------- flash attention, compacted q-rows ----------------
__global__ void __launch_bounds__(256) attn_kernel(const bf16* __restrict__ qkv,
    const bf16* __restrict__ vtg, bf16* __restrict__ ctx,
    const int* __restrict__ bidx, const int* __restrict__ bcnt) {
  __shared__ bf16 Qs[64 * 72];
  __shared__ bf16 Ks[64 * 72];
  __shared__ bf16 Vt[64 * 72];
  __shared__ bf16 Ps[64 * 72];
  __shared__ int Ts[64];
  const int tid = threadIdx.x;
  const int w = tid >> 6, lane = tid & 63;
  const int lr = lane & 15, lq = lane >> 4;
  const int blk = blockIdx.x;
  const int bh = (blk & 7) | ((blk >> 7) << 3);
  const int qt = (blk >> 3) & 15;
  const int b = bh >> 4, h = bh & 15;
  const int nb = bcnt[b];
  if (qt * 64 >= nb) return;
  const size_t rowbase = (size_t)b * 1024;
  const int hcol = h * 64;
  const size_t vbase = (size_t)bh * 65536;

  if (tid < 64) {
    const int j = qt * 64 + tid;
    Ts[tid] = (j < nb) ? bidx[b * 1024 + j] : bidx[b * 1024 + qt * 64];
  }
  __syncthreads();

#pragma unroll
  for (int i = 0; i < 2; i++) {
    const int c = tid + i * 256;
    const int r = c >> 3, k8 = (c & 7) * 8;
    uint4 v = *(const uint4*)&qkv[(rowbase + Ts[r]) * 3072 + hcol + k8];
    *(uint4*)&Qs[r * 72 + k8] = v;
  }
  __syncthreads();
  bf16x8 aq[2];
#pragma unroll
  for (int hs = 0; hs < 2; hs++)
    aq[hs] = *(const bf16x8*)&Qs[(w * 16 + lr) * 72 + hs * 32 + lq * 8];

  float lsum[4] = {0.0f, 0.0f, 0.0f, 0.0f};
  f32x4 o[4];
#pragma unroll
  for (int i = 0; i < 4; i++) o[i] = (f32x4)0.0f;

  const int Sw = ((w * 4 + lq) & 7) << 3;
  const int Sr = ((w * 4 + (lr >> 2)) & 7) << 3;

  for (int kb = 0; kb < 16; kb++) {
    __syncthreads();
#pragma unroll
    for (int i = 0; i < 2; i++) {
      const int c = tid + i * 256;
      const int r = c >> 3, k8 = (c & 7) * 8;
      uint4 v = *(const uint4*)&qkv[(rowbase + kb * 64 + r) * 3072 + 1024 + hcol + k8];
      *(uint4*)&Ks[r * 72 + k8] = v;
    }
#pragma unroll
    for (int i = 0; i < 2; i++) {
      const int c = tid + i * 256;
      const int hd = c >> 3, t8 = (c & 7) * 8;
      uint4 v = *(const uint4*)&vtg[vbase + (size_t)hd * 1024 + kb * 64 + t8];
      *(uint4*)&Vt[hd * 72 + (t8 ^ (hd & 56))] = v;
    }
    __syncthreads();

    f32x4 s[4];
#pragma unroll
    for (int kf = 0; kf < 4; kf++) {
      f32x4 sa = (f32x4)0.0f;
#pragma unroll
      for (int hs = 0; hs < 2; hs++) {
        bf16x8 bk = *(const bf16x8*)&Ks[(kf * 16 + lr) * 72 + hs * 32 + lq * 8];
        sa = __builtin_amdgcn_mfma_f32_16x16x32_bf16(aq[hs], bk, sa, 0, 0, 0);
      }
      s[kf] = sa;
    }

#pragma unroll
    for (int kf = 0; kf < 4; kf++) {
#pragma unroll
      for (int r = 0; r < 4; r++) {
        const float p = __expf(s[kf][r] * 0.125f);
        lsum[r] += p;
        const int row = w * 16 + lq * 4 + r;
        Ps[row * 72 + ((kf * 16 + lr) ^ Sw)] = (bf16)p;
      }
    }

    bf16x8 ap[2];
#pragma unroll
    for (int ks = 0; ks < 2; ks++)
      ap[ks] = *(const bf16x8*)&Ps[(w * 16 + lr) * 72 + ((ks * 32 + lq * 8) ^ Sr)];
#pragma unroll
    for (int hf = 0; hf < 4; hf++) {
      const int vrow = hf * 16 + lr;
#pragma unroll
      for (int ks = 0; ks < 2; ks++) {
        bf16x8 bv = *(const bf16x8*)&Vt[vrow * 72 + ((ks * 32 + lq * 8) ^ (vrow & 56))];
        o[hf] = __builtin_amdgcn_mfma_f32_16x16x32_bf16(ap[ks], bv, o[hf], 0, 0, 0);
      }
    }
  }

#pragma unroll
  for (int r = 0; r < 4; r++) {
#pragma unroll
    for (int d = 1; d < 16; d <<= 1) lsum[r] += __shfl_xor(lsum[r], d, 64);
  }

#pragma unroll
  for (int r = 0; r < 4; r++) {
    const int rowj = w * 16 + lq * 4 + r;
    if (qt * 64 + rowj < nb) {
      const float inv = 1.0f / lsum[r];
      const size_t row = rowbase + Ts[rowj];
#pragma unroll
      for (int hf = 0; hf < 4; hf++)
        ctx[row * 1024 + hcol + hf * 16 + lr] = (bf16)(o[hf][r] * inv);
    }
  }
}

// ---------------- launch ----------------
extern "C" void kernel_launch(void* const* d_in, const int* in_sizes, int n_in,
                              void* d_out, int out_size, void* d_ws, size_t ws_size,
                              hipStream_t stream) {
  (void)in_sizes; (void)n_in; (void)out_size; (void)ws_size;
  const float* x    = (const float*)d_in[0];
  const float* a_nw = (const float*)d_in[1];
  const float* a_nb = (const float*)d_in[2];
  const float* in_w = (const float*)d_in[3];
  const float* in_b = (const float*)d_in[4];
  const float* o_w  = (const float*)d_in[5];
  const float* o_b  = (const float*)d_in[6];
  const float* f_nw = (const float*)d_in[7];
  const float* f_nb = (const float*)d_in[8];
  const float* w1   = (const float*)d_in[9];
  const float* b1   = (const float*)d_in[10];
  const float* w2   = (const float*)d_in[11];
  const float* b2   = (const float*)d_in[12];
  const float* r_nw = (const float*)d_in[13];
  const float* r_nb = (const float*)d_in[14];
  const float* rw1  = (const float*)d_in[15];
  const float* rb1  = (const float*)d_in[16];
  const float* rw2  = (const float*)d_in[17];
  const float* rb2  = (const float*)d_in[18];

  float* cur    = (float*)d_out;
  float* depths = cur + 8388608;
  float* logits = depths + 8192;

  char* ws = (char*)d_ws;
  bf16* wb_in  = (bf16*)(ws + 0);
  bf16* wb_out = (bf16*)(ws + 6291456);
  bf16* wb_f1  = (bf16*)(ws + 8388608);
  bf16* wb_f2  = (bf16*)(ws + 16777216);
  bf16* r1h    = (bf16*)(ws + 25165824);
  bf16* r1m    = (bf16*)(ws + 27262976);
  bf16* r1l    = (bf16*)(ws + 29360128);
  bf16* Abuf   = (bf16*)(ws + 31457280);
  bf16* Bbuf   = (bf16*)(ws + 48234496);
  bf16* Big    = (bf16*)(ws + 65011712);
  float* Tmp   = (float*)(ws + 132120576);
  bf16* VtG    = (bf16*)(ws + 132120576);   // aliases Tmp: live ranges disjoint
  int*  gate   = (int*)(ws + 165675008);
  // idx/cnt arrays alias the router split-weight buffers (dead after gemm_router)
  int* idx_all  = (int*)(ws + 25165824);    // 6*8192 ints (aliases r1h)
  int* bidx_all = (int*)(ws + 27262976);    // 6*8192 ints (aliases r1m)
  int* cnt_all  = (int*)(ws + 29360128);    // 6 ints      (aliases r1l)
  int* bcnt_all = cnt_all + 16;             // 48 ints

  hipMemcpyAsync(cur, x, (size_t)8388608 * 4, hipMemcpyDeviceToDevice, stream);

  f2b_kernel<<<3072, 256, 0, stream>>>(in_w, wb_in, 3145728);
  f2b_kernel<<<1024, 256, 0, stream>>>(o_w, wb_out, 1048576);
  f2b_kernel<<<4096, 256, 0, stream>>>(w1, wb_f1, 4194304);
  f2b_kernel<<<4096, 256, 0, stream>>>(w2, wb_f2, 4194304);
  split3_kernel<<<1024, 256, 0, stream>>>(rw1, r1h, r1m, r1l, 1048576);

  // ---- router ----
  ln_kernel<3><<<8192, 256, 0, stream>>>(x, r_nw, r_nb, Abuf, Bbuf, Big);
  gemm_router<<<dim3(8, 64), 256, 0, stream>>>(Abuf, Bbuf, Big, r1h, r1m, r1l, Tmp);
  gelu_bias_kernel<<<8192, 256, 0, stream>>>(Tmp, rb1, 8388608);
  router_logits<<<2048, 256, 0, stream>>>(Tmp, rw2, rb2, logits, depths, gate);
  zero_cnt_kernel<<<1, 64, 0, stream>>>(cnt_all, bcnt_all);
  build_idx_kernel<<<48, 256, 0, stream>>>(gate, idx_all, cnt_all, bidx_all, bcnt_all);

  // ---- 6 recursion levels, depth-compacted ----
  for (int level = 1; level <= 6; level++) {
    const int lev = level - 1;
    const int* idxL  = idx_all + lev * 8192;
    const int* cntL  = cnt_all + lev;
    const int* bidxL = bidx_all + lev * 8192;
    const int* bcntL = bcnt_all + lev * 8;

    ln_kernel<1><<<8192, 256, 0, stream>>>(cur, a_nw, a_nb, Abuf, nullptr, nullptr);
    // K,V projection: all rows (frozen tokens still serve as keys/values)
    gemm256<0, 256><<<dim3(8, 32), 512, 0, stream>>>(Abuf, wb_in + 1048576, in_b + 1024,
        nullptr, nullptr, Big, nullptr, nullptr, 2048, 1024, 3072, 1024);
    // Q projection: active rows only, scatter into Big
    gemm256<1, 128><<<dim3(8, 32), 512, 0, stream>>>(Abuf, wb_in, in_b,
        nullptr, nullptr, Big, idxL, cntL, 1024, 1024, 3072, 0);
    vtrans_kernel<<<2048, 256, 0, stream>>>(Big, VtG);
    attn_kernel<<<2048, 256, 0, stream>>>(Big, VtG, Bbuf, bidxL, bcntL);
    // out-proj: gather ctx + residual, compact output
    gemm256<2, 128><<<dim3(8, 32), 512, 0, stream>>>(Bbuf, wb_out, o_b,
        cur, Tmp, nullptr, idxL, cntL, 1024, 1024, 0, 0);
    ln_c_kernel<<<8192, 256, 0, stream>>>(Tmp, f_nw, f_nb, Abuf, cntL);
    gemm256<3, 256><<<dim3(16, 32), 512, 0, stream>>>(Abuf, wb_f1, b1,
        nullptr, nullptr, Big, idxL, cntL, 4096, 1024, 0, 0);
    gemm256<4, 128><<<dim3(8, 32), 512, 0, stream>>>(Big, wb_f2, b2,
        Tmp, cur, nullptr, idxL, cntL, 1024, 4096, 0, 0);
  }
}

// Round 2
// 2345.459 us; speedup vs baseline: 1.1136x; 1.0065x over previous
//
#include <hip/hip_runtime.h>
#include <cstdint>
#include <cstddef>

typedef __bf16 bf16;
typedef bf16 bf16x8 __attribute__((ext_vector_type(8)));
typedef float f32x4 __attribute__((ext_vector_type(4)));

#define GAS __attribute__((address_space(1)))
#define LAS __attribute__((address_space(3)))

__device__ __forceinline__ void async_cp16(const bf16* g, bf16* l) {
  __builtin_amdgcn_global_load_lds((const GAS unsigned int*)g,
                                   (LAS unsigned int*)l, 16, 0, 0);
}

__device__ __forceinline__ float gelu_f(float x) {
  return 0.5f * x * (1.0f + erff(x * 0.70710678118654752440f));
}

// ---------------- weight conversion ----------------
__global__ void __launch_bounds__(256) f2b_kernel(const float* __restrict__ in,
                                                  bf16* __restrict__ out, int n) {
  int i = (blockIdx.x * 256 + threadIdx.x) * 4;
  if (i >= n) return;
  float4 v = *(const float4*)&in[i];
  union { uint2 u; bf16 e[4]; } o;
  o.e[0] = (bf16)v.x; o.e[1] = (bf16)v.y; o.e[2] = (bf16)v.z; o.e[3] = (bf16)v.w;
  *(uint2*)&out[i] = o.u;
}

__global__ void __launch_bounds__(256) split3_kernel(const float* __restrict__ in,
    bf16* __restrict__ oh, bf16* __restrict__ om, bf16* __restrict__ ol, int n) {
  int i = (blockIdx.x * 256 + threadIdx.x) * 4;
  if (i >= n) return;
  float4 v = *(const float4*)&in[i];
  float a[4] = {v.x, v.y, v.z, v.w};
  union { uint2 u; bf16 e[4]; } h, m, l;
#pragma unroll
  for (int j = 0; j < 4; j++) {
    h.e[j] = (bf16)a[j];
    float r = a[j] - (float)h.e[j];
    m.e[j] = (bf16)r;
    l.e[j] = (bf16)(r - (float)m.e[j]);
  }
  *(uint2*)&oh[i] = h.u;
  *(uint2*)&om[i] = m.u;
  *(uint2*)&ol[i] = l.u;
}

// ---------------- layernorm (full M; optional 3-way split) ----------------
template<int SPLIT>
__global__ void __launch_bounds__(256) ln_kernel(const float* __restrict__ X,
    const float* __restrict__ w, const float* __restrict__ b,
    bf16* __restrict__ oh, bf16* __restrict__ om, bf16* __restrict__ ol) {
  const int row = blockIdx.x;
  const int tid = threadIdx.x;
  const float4 xv = *(const float4*)&X[(size_t)row * 1024 + tid * 4];
  float s1 = xv.x + xv.y + xv.z + xv.w;
  float s2 = xv.x * xv.x + xv.y * xv.y + xv.z * xv.z + xv.w * xv.w;
#pragma unroll
  for (int d = 1; d < 64; d <<= 1) {
    s1 += __shfl_xor(s1, d, 64);
    s2 += __shfl_xor(s2, d, 64);
  }
  __shared__ float red[8];
  if ((tid & 63) == 0) { red[tid >> 6] = s1; red[4 + (tid >> 6)] = s2; }
  __syncthreads();
  s1 = red[0] + red[1] + red[2] + red[3];
  s2 = red[4] + red[5] + red[6] + red[7];
  const float mu = s1 * (1.0f / 1024.0f);
  const float var = s2 * (1.0f / 1024.0f) - mu * mu;
  const float rs = rsqrtf(var + 1e-5f);
  const float4 wv = *(const float4*)&w[tid * 4];
  const float4 bv = *(const float4*)&b[tid * 4];
  float y[4] = {(xv.x - mu) * rs * wv.x + bv.x,
                (xv.y - mu) * rs * wv.y + bv.y,
                (xv.z - mu) * rs * wv.z + bv.z,
                (xv.w - mu) * rs * wv.w + bv.w};
  union { uint2 u; bf16 e[4]; } h;
#pragma unroll
  for (int j = 0; j < 4; j++) h.e[j] = (bf16)y[j];
  *(uint2*)&oh[(size_t)row * 1024 + tid * 4] = h.u;
  if (SPLIT == 3) {
    union { uint2 u; bf16 e[4]; } m, l;
#pragma unroll
    for (int j = 0; j < 4; j++) {
      float r = y[j] - (float)h.e[j];
      m.e[j] = (bf16)r;
      l.e[j] = (bf16)(r - (float)m.e[j]);
    }
    *(uint2*)&om[(size_t)row * 1024 + tid * 4] = m.u;
    *(uint2*)&ol[(size_t)row * 1024 + tid * 4] = l.u;
  }
}

// ---------------- layernorm on compacted rows, zero-fill to 128-pad ----------------
__global__ void __launch_bounds__(256) ln_c_kernel(const float* __restrict__ X,
    const float* __restrict__ w, const float* __restrict__ b,
    bf16* __restrict__ oh, const int* __restrict__ cnt_ptr) {
  const int row = blockIdx.x;
  const int cnt = *cnt_ptr;
  const int pad = (cnt + 127) & ~127;
  if (row >= pad) return;
  const int tid = threadIdx.x;
  if (row >= cnt) {
    *(uint2*)&oh[(size_t)row * 1024 + tid * 4] = make_uint2(0, 0);
    return;
  }
  const float4 xv = *(const float4*)&X[(size_t)row * 1024 + tid * 4];
  float s1 = xv.x + xv.y + xv.z + xv.w;
  float s2 = xv.x * xv.x + xv.y * xv.y + xv.z * xv.z + xv.w * xv.w;
#pragma unroll
  for (int d = 1; d < 64; d <<= 1) {
    s1 += __shfl_xor(s1, d, 64);
    s2 += __shfl_xor(s2, d, 64);
  }
  __shared__ float red[8];
  if ((tid & 63) == 0) { red[tid >> 6] = s1; red[4 + (tid >> 6)] = s2; }
  __syncthreads();
  s1 = red[0] + red[1] + red[2] + red[3];
  s2 = red[4] + red[5] + red[6] + red[7];
  const float mu = s1 * (1.0f / 1024.0f);
  const float var = s2 * (1.0f / 1024.0f) - mu * mu;
  const float rs = rsqrtf(var + 1e-5f);
  const float4 wv = *(const float4*)&w[tid * 4];
  const float4 bv = *(const float4*)&b[tid * 4];
  union { uint2 u; bf16 e[4]; } h;
  h.e[0] = (bf16)((xv.x - mu) * rs * wv.x + bv.x);
  h.e[1] = (bf16)((xv.y - mu) * rs * wv.y + bv.y);
  h.e[2] = (bf16)((xv.z - mu) * rs * wv.z + bv.z);
  h.e[3] = (bf16)((xv.w - mu) * rs * wv.w + bv.w);
  *(uint2*)&oh[(size_t)row * 1024 + tid * 4] = h.u;
}

// ---------------- depth-compaction index build ----------------
__global__ void zero_cnt_kernel(int* cnt_all, int* bcnt_all) {
  if (threadIdx.x < 6) cnt_all[threadIdx.x] = 0;
  if (threadIdx.x < 48) bcnt_all[threadIdx.x] = 0;
}

__global__ void __launch_bounds__(256) build_idx_kernel(
    const int* __restrict__ gate, int* __restrict__ idx_all,
    int* __restrict__ cnt_all, int* __restrict__ bidx_all,
    int* __restrict__ bcnt_all) {
  const int lev = blockIdx.x >> 3;   // 0..5
  const int b   = blockIdx.x & 7;
  const int level = lev + 1;
  int* idx  = idx_all + lev * 8192;
  int* bidx = bidx_all + lev * 8192 + b * 1024;
  for (int t = threadIdx.x; t < 1024; t += 256) {
    const int row = b * 1024 + t;
    if (gate[row] >= level) {
      int p = atomicAdd(&bcnt_all[lev * 8 + b], 1);
      bidx[p] = t;
      int q = atomicAdd(&cnt_all[lev], 1);
      idx[q] = row;
    }
  }
}

// XCD-aware block remap (128-tile version, used by gemm_router).
__device__ __forceinline__ void swizzle_mn(int gx, int& m0, int& n0) {
  const int id = blockIdx.y * gx + blockIdx.x;
  const int k8 = id & 7, t = id >> 3;
  n0 = (t % gx) * 128;
  m0 = ((t / gx) * 8 + k8) * 128;
}

// ================= 256-row-tile 8-wave 4-phase pipelined NT GEMM =================
// Same structure as round-1, but DE-PINNED: no sched_barrier(0), no explicit
// lgkmcnt(0) — the compiler inserts fine-grained lgkmcnt(N) before each MFMA
// (m97/m141 evidence: full-drain + order-pinning costs ~1.7x). Raw barriers,
// setprio around the MFMA cluster, and counted vmcnt (compiler can't derive
// those) are kept. Cross-wave staging safety: every ds_read is consumed by an
// MFMA before the phase's closing barrier, so by the time stageB(bf, t+2) is
// issued at p2 all waves have finished reading B(t); s_barrier has unmodeled
// side effects so global_load_lds (a write) cannot be compiler-hoisted across.
template<int MODE, int BN>
__global__ void __launch_bounds__(512, 2) gemm256(
    const bf16* __restrict__ A, const bf16* __restrict__ B,
    const float* __restrict__ bias, const float* __restrict__ Res,
    float* __restrict__ C32, bf16* __restrict__ Cb,
    const int* __restrict__ idx, const int* __restrict__ cnt_ptr,
    int N, int K, int ldc, int coff) {
  __shared__ bf16 lds[65536];   // 128 KiB: A halves [0,32768), B halves [32768,65536)
  const int tid = threadIdx.x;
  const int w = tid >> 6, lane = tid & 63;
  const int lr = lane & 15, lq = lane >> 4;
  constexpr int MI  = (BN == 256) ? 8 : 4;   // A frags per wave
  constexpr int MPH = (BN == 256) ? 2 : 1;   // A frags per phase
  constexpr int NBH = (BN == 256) ? 2 : 1;   // B half-tiles
  const int wr = (BN == 256) ? (w >> 2) : (w >> 1);
  const int wc = (BN == 256) ? (w & 3) : (w & 1);

  // XCD-aware tile coords (grid.x * grid.y is a multiple of 8 in all call sites)
  const int gx = gridDim.x;
  const int id = blockIdx.y * gx + blockIdx.x;
  const int k8 = id & 7, tt = id >> 3;
  const int n0 = (tt % gx) * BN;
  const int m0 = ((tt / gx) * 8 + k8) * 256;

  int cnt = 0x7fffffff;
  if (MODE != 0) {
    cnt = *cnt_ptr;
    if (m0 >= cnt) return;
  }

  const int NT = K >> 6;

  // ---- staging source pointers (per-thread, swizzled k-chunk) ----
  const int srow  = tid >> 3;                       // 0..63
  const int skoff = ((tid & 7) ^ (srow & 7)) * 8;   // LDS[row][slot]=G[row][slot^(row&7)]
  const bf16* gA[4];
#pragma unroll
  for (int h = 0; h < 2; h++)
#pragma unroll
    for (int j = 0; j < 2; j++) {
      const int i = m0 + h * 128 + j * 64 + srow;
      size_t ar;
      if (MODE == 1 || MODE == 2) ar = (size_t)idx[i < cnt ? i : 0];
      else ar = (size_t)i;
      gA[h * 2 + j] = A + ar * (size_t)K + skoff;
    }
  const bf16* gB[4];
#pragma unroll
  for (int h = 0; h < NBH; h++)
#pragma unroll
    for (int j = 0; j < 2; j++)
      gB[h * 2 + j] = B + (size_t)(n0 + h * 128 + j * 64 + srow) * K + skoff;

  auto stageA = [&](int bf, int h, int t) {
#pragma unroll
    for (int j = 0; j < 2; j++)
      async_cp16(gA[h * 2 + j] + (size_t)t * 64,
                 &lds[(bf * 2 + h) * 8192 + (j * 64 + w * 8) * 64]);
  };
  auto stageB = [&](int bf, int h, int t) {
#pragma unroll
    for (int j = 0; j < 2; j++)
      async_cp16(gB[h * 2 + j] + (size_t)t * 64,
                 &lds[32768 + (bf * 2 + h) * 8192 + (j * 64 + w * 8) * 64]);
  };

  // ---- fragment read helpers (swizzled) ----
  const int ah  = (BN == 256) ? wr : (wr >> 1);          // A half for this wave
  const int arb = (BN == 256) ? 0 : ((wr & 1) * 64);     // row base within half
  const int bh  = (BN == 256) ? (wc >> 1) : 0;
  const int brb = (BN == 256) ? ((wc & 1) * 64) : (wc * 64);
  const int swz = (lr & 7);
  auto rdA = [&](int bf, int mi, int ks) {
    return *(const bf16x8*)&lds[(bf * 2 + ah) * 8192 + (arb + mi * 16 + lr) * 64
                                + (((ks * 4 + lq) ^ swz) * 8)];
  };
  auto rdB = [&](int bf, int ni, int ks) {
    return *(const bf16x8*)&lds[32768 + (bf * 2 + bh) * 8192
                                + (brb + ni * 16 + lr) * 64
                                + (((ks * 4 + lq) ^ swz) * 8)];
  };

  f32x4 acc[MI][4] = {};
  bf16x8 bq[4][2];

  // ---- prologue: tile0 fully + B(1); A(1) is staged inside t=0 ----
  stageA(0, 0, 0); stageA(0, 1, 0);
  stageB(0, 0, 0);
  if (BN == 256) stageB(0, 1, 0);
  stageB(1, 0, 1);
  if (BN == 256) stageB(1, 1, 1);
  asm volatile("s_waitcnt vmcnt(0)" ::: "memory");
  __builtin_amdgcn_s_barrier();

  for (int t = 0; t < NT; ++t) {
    const int bf = t & 1;
#pragma unroll
    for (int p = 0; p < 4; ++p) {
      bf16x8 af[2 * MPH];
#pragma unroll
      for (int m = 0; m < MPH; m++)
#pragma unroll
        for (int ks = 0; ks < 2; ks++)
          af[m * 2 + ks] = rdA(bf, p * MPH + m, ks);
      if (p == 0) {
#pragma unroll
        for (int ni = 0; ni < 4; ni++)
#pragma unroll
          for (int ks = 0; ks < 2; ks++)
            bq[ni][ks] = rdB(bf, ni, ks);
      }
      // one half-tile stage per phase
      if (p == 0)      { if (t + 1 < NT) stageA(bf ^ 1, 0, t + 1); }
      else if (p == 1) { if (t + 1 < NT) stageA(bf ^ 1, 1, t + 1); }
      else if (p == 2) { if (t + 2 < NT) stageB(bf, 0, t + 2); }
      else if (BN == 256) { if (t + 2 < NT) stageB(bf, 1, t + 2); }

      __builtin_amdgcn_s_barrier();
      // no explicit lgkmcnt(0)/sched_barrier: compiler inserts fine-grained
      // lgkmcnt(N) before each MFMA and may overlap issue with the cluster.
      __builtin_amdgcn_s_setprio(1);
#pragma unroll
      for (int m = 0; m < MPH; m++) {
        const int mi = p * MPH + m;
#pragma unroll
        for (int ni = 0; ni < 4; ni++) {
          acc[mi][ni] = __builtin_amdgcn_mfma_f32_16x16x32_bf16(
              af[m * 2 + 0], bq[ni][0], acc[mi][ni], 0, 0, 0);
          acc[mi][ni] = __builtin_amdgcn_mfma_f32_16x16x32_bf16(
              af[m * 2 + 1], bq[ni][1], acc[mi][ni], 0, 0, 0);
        }
      }
      __builtin_amdgcn_s_setprio(0);
      if (p == 3) {
        if (t + 2 < NT) {
          if constexpr (BN == 256) asm volatile("s_waitcnt vmcnt(4)" ::: "memory");
          else                     asm volatile("s_waitcnt vmcnt(2)" ::: "memory");
        } else {
          asm volatile("s_waitcnt vmcnt(0)" ::: "memory");
        }
      }
      __builtin_amdgcn_s_barrier();
    }
  }

  // ---- epilogue (same semantics as old gemm_nt) ----
  const int rw = m0 + ((BN == 256) ? wr * 128 : wr * 64);
#pragma unroll
  for (int mi = 0; mi < MI; mi++) {
    const int rbase = rw + mi * 16 + lq * 4;
    int orig[4];
#pragma unroll
    for (int r = 0; r < 4; r++) {
      const int i = rbase + r;
      if (MODE == 1 || MODE == 2 || MODE == 4) orig[r] = (i < cnt) ? idx[i] : -1;
      else orig[r] = i;
    }
#pragma unroll
    for (int ni = 0; ni < 4; ni++) {
      const int c = n0 + wc * 64 + ni * 16 + lr;
      const float bv = bias[c];
#pragma unroll
      for (int r = 0; r < 4; r++) {
        const float v = acc[mi][ni][r] + bv;
        const int i = rbase + r;
        if (MODE == 0) {
          Cb[(size_t)i * ldc + coff + c] = (bf16)v;
        } else if (MODE == 1) {
          if (orig[r] >= 0) Cb[(size_t)orig[r] * ldc + c] = (bf16)v;
        } else if (MODE == 2) {
          const float rv = (orig[r] >= 0) ? Res[(size_t)orig[r] * N + c] : 0.0f;
          C32[(size_t)i * N + c] = rv + v;
        } else if (MODE == 3) {
          Cb[(size_t)i * N + c] = (bf16)gelu_f(v);
        } else {
          if (orig[r] >= 0)
            C32[(size_t)orig[r] * N + c] = Res[(size_t)i * N + c] + v;
        }
      }
    }
  }
}

// ---------------- fused 6-product split-bf16 router GEMM ----------------
__global__ void __launch_bounds__(256) gemm_router(
    const bf16* __restrict__ Ah, const bf16* __restrict__ Am, const bf16* __restrict__ Al,
    const bf16* __restrict__ Bh, const bf16* __restrict__ Bm, const bf16* __restrict__ Bl,
    float* __restrict__ C32) {
  __shared__ bf16 As[3][128 * 32];
  __shared__ bf16 Bs[3][128 * 32];
  const int tid = threadIdx.x;
  const int w = tid >> 6, lane = tid & 63;
  const int lr = lane & 15, lq = lane >> 4;
  int m0, n0;
  swizzle_mn(gridDim.x, m0, n0);
  const int wm = (w >> 1) * 64, wn = (w & 1) * 64;
  const int K = 1024;

  f32x4 acc[4][4] = {};

  const size_t aoff = (size_t)(m0 + (tid >> 2)) * K + (tid & 3) * 8;
  const size_t boff = (size_t)(n0 + (tid >> 2)) * K + (tid & 3) * 8;
  const bf16* gA[3] = {Ah + aoff, Am + aoff, Al + aoff};
  const bf16* gB[3] = {Bh + boff, Bm + boff, Bl + boff};
  const int lo = w * 512;
  const size_t step64 = (size_t)64 * K;

  const int cA[6] = {0, 0, 1, 1, 0, 2};
  const int cB[6] = {0, 1, 0, 1, 2, 0};

  for (int k0 = 0; k0 < K; k0 += 32) {
    __syncthreads();
#pragma unroll
    for (int j = 0; j < 3; j++) {
      async_cp16(gA[j] + k0, As[j] + lo);
      async_cp16(gA[j] + step64 + k0, As[j] + lo + 2048);
      async_cp16(gB[j] + k0, Bs[j] + lo);
      async_cp16(gB[j] + step64 + k0, Bs[j] + lo + 2048);
    }
    __syncthreads();
#pragma unroll
    for (int c = 0; c < 6; c++) {
      bf16x8 af[4], bfr[4];
#pragma unroll
      for (int i = 0; i < 4; i++)
        af[i] = *(const bf16x8*)&As[cA[c]][(wm + i * 16 + lr) * 32 + lq * 8];
#pragma unroll
      for (int i = 0; i < 4; i++)
        bfr[i] = *(const bf16x8*)&Bs[cB[c]][(wn + i * 16 + lr) * 32 + lq * 8];
#pragma unroll
      for (int mi = 0; mi < 4; mi++)
#pragma unroll
        for (int ni = 0; ni < 4; ni++)
          acc[mi][ni] = __builtin_amdgcn_mfma_f32_16x16x32_bf16(
              af[mi], bfr[ni], acc[mi][ni], 0, 0, 0);
    }
  }

#pragma unroll
  for (int mi = 0; mi < 4; mi++) {
    const int rbase = m0 + wm + mi * 16 + lq * 4;
#pragma unroll
    for (int ni = 0; ni < 4; ni++) {
      const int c = n0 + wn + ni * 16 + lr;
#pragma unroll
      for (int r = 0; r < 4; r++)
        C32[(size_t)(rbase + r) * 1024 + c] = acc[mi][ni][r];
    }
  }
}

// ---------------- router tail ----------------
__global__ void __launch_bounds__(256) gelu_bias_kernel(float* __restrict__ t,
    const float* __restrict__ bias, int n) {
  int i = (blockIdx.x * 256 + threadIdx.x) * 4;
  if (i >= n) return;
  float4 v = *(const float4*)&t[i];
  float4 bb = *(const float4*)&bias[i & 1023];
  v.x = gelu_f(v.x + bb.x);
  v.y = gelu_f(v.y + bb.y);
  v.z = gelu_f(v.z + bb.z);
  v.w = gelu_f(v.w + bb.w);
  *(float4*)&t[i] = v;
}

__global__ void __launch_bounds__(256) router_logits(const float* __restrict__ h,
    const float* __restrict__ w2, const float* __restrict__ b2,
    float* __restrict__ logits_out, float* __restrict__ depths_out,
    int* __restrict__ gate) {
  const int row = blockIdx.x * 4 + (threadIdx.x >> 6);
  const int lane = threadIdx.x & 63;
  const float* hr = h + (size_t)row * 1024;
  float part[6] = {0, 0, 0, 0, 0, 0};
  for (int kc = lane; kc < 256; kc += 64) {
    float4 hv = *(const float4*)&hr[kc * 4];
#pragma unroll
    for (int j = 0; j < 6; j++) {
      float4 wv = *(const float4*)&w2[j * 1024 + kc * 4];
      part[j] += hv.x * wv.x + hv.y * wv.y + hv.z * wv.z + hv.w * wv.w;
    }
  }
#pragma unroll
  for (int j = 0; j < 6; j++)
#pragma unroll
    for (int d = 1; d < 64; d <<= 1) part[j] += __shfl_xor(part[j], d, 64);
  if (lane == 0) {
    float best = -1e30f;
    int bi = 0;
#pragma unroll
    for (int j = 0; j < 6; j++) {
      const float v = part[j] + b2[j];
      logits_out[(size_t)row * 6 + j] = v;
      if (v > best) { best = v; bi = j; }
    }
    depths_out[row] = (float)(bi + 1);
    gate[row] = bi + 1;
  }
}

// ---------------- V transpose ----------------
__global__ void __launch_bounds__(256) vtrans_kernel(const bf16* __restrict__ qkv,
                                                     bf16* __restrict__ vt) {
  __shared__ bf16 T[64 * 64];
  const int tid = threadIdx.x;
  const int tb = blockIdx.x & 15, bh = blockIdx.x >> 4;
  const int b = bh >> 4, h = bh & 15;
#pragma unroll
  for (int i = 0; i < 2; i++) {
    const int c = tid + i * 256;
    const int tok = c >> 3, hd8 = (c & 7) * 8;
    uint4 v = *(const uint4*)&qkv[((size_t)b * 1024 + tb * 64 + tok) * 3072 + 2048 + h * 64 + hd8];
    *(uint4*)&T[tok * 64 + (hd8 ^ ((tok & 7) << 3))] = v;
  }
  __syncthreads();
#pragma unroll
  for (int i = 0; i < 2; i++) {
    const int c = tid + i * 256;
    const int hd = c >> 3, t8 = (c & 7) * 8;
    union { uint4 u; bf16 e[8]; } o;
#pragma unroll
    for (int j = 0; j < 8; j++)
      o.e[j] = T[(t8 + j) * 64 + (hd ^ (j << 3))];
    *(uint4*)&vt[((size_t)bh * 64 + hd) * 1024 + tb * 64 + t8] = o.u;
  }
}

// ---------------- flash attention, compacted q-rows ----------------
__global__ void __launch_bounds__(256) attn_kernel(const bf16* __restrict__ qkv,
    const bf16* __restrict__ vtg, bf16* __restrict__ ctx,
    const int* __restrict__ bidx, const int* __restrict__ bcnt) {
  __shared__ bf16 Qs[64 * 72];
  __shared__ bf16 Ks[64 * 72];
  __shared__ bf16 Vt[64 * 72];
  __shared__ bf16 Ps[64 * 72];
  __shared__ int Ts[64];
  const int tid = threadIdx.x;
  const int w = tid >> 6, lane = tid & 63;
  const int lr = lane & 15, lq = lane >> 4;
  const int blk = blockIdx.x;
  const int bh = (blk & 7) | ((blk >> 7) << 3);
  const int qt = (blk >> 3) & 15;
  const int b = bh >> 4, h = bh & 15;
  const int nb = bcnt[b];
  if (qt * 64 >= nb) return;
  const size_t rowbase = (size_t)b * 1024;
  const int hcol = h * 64;
  const size_t vbase = (size_t)bh * 65536;

  if (tid < 64) {
    const int j = qt * 64 + tid;
    Ts[tid] = (j < nb) ? bidx[b * 1024 + j] : bidx[b * 1024 + qt * 64];
  }
  __syncthreads();

#pragma unroll
  for (int i = 0; i < 2; i++) {
    const int c = tid + i * 256;
    const int r = c >> 3, k8 = (c & 7) * 8;
    uint4 v = *(const uint4*)&qkv[(rowbase + Ts[r]) * 3072 + hcol + k8];
    *(uint4*)&Qs[r * 72 + k8] = v;
  }
  __syncthreads();
  bf16x8 aq[2];
#pragma unroll
  for (int hs = 0; hs < 2; hs++)
    aq[hs] = *(const bf16x8*)&Qs[(w * 16 + lr) * 72 + hs * 32 + lq * 8];

  float lsum[4] = {0.0f, 0.0f, 0.0f, 0.0f};
  f32x4 o[4];
#pragma unroll
  for (int i = 0; i < 4; i++) o[i] = (f32x4)0.0f;

  const int Sw = ((w * 4 + lq) & 7) << 3;
  const int Sr = ((w * 4 + (lr >> 2)) & 7) << 3;

  for (int kb = 0; kb < 16; kb++) {
    __syncthreads();
#pragma unroll
    for (int i = 0; i < 2; i++) {
      const int c = tid + i * 256;
      const int r = c >> 3, k8 = (c & 7) * 8;
      uint4 v = *(const uint4*)&qkv[(rowbase + kb * 64 + r) * 3072 + 1024 + hcol + k8];
      *(uint4*)&Ks[r * 72 + k8] = v;
    }
#pragma unroll
    for (int i = 0; i < 2; i++) {
      const int c = tid + i * 256;
      const int hd = c >> 3, t8 = (c & 7) * 8;
      uint4 v = *(const uint4*)&vtg[vbase + (size_t)hd * 1024 + kb * 64 + t8];
      *(uint4*)&Vt[hd * 72 + (t8 ^ (hd & 56))] = v;
    }
    __syncthreads();

    f32x4 s[4];
#pragma unroll
    for (int kf = 0; kf < 4; kf++) {
      f32x4 sa = (f32x4)0.0f;
#pragma unroll
      for (int hs = 0; hs < 2; hs++) {
        bf16x8 bk = *(const bf16x8*)&Ks[(kf * 16 + lr) * 72 + hs * 32 + lq * 8];
        sa = __builtin_amdgcn_mfma_f32_16x16x32_bf16(aq[hs], bk, sa, 0, 0, 0);
      }
      s[kf] = sa;
    }

#pragma unroll
    for (int kf = 0; kf < 4; kf++) {
#pragma unroll
      for (int r = 0; r < 4; r++) {
        const float p = __expf(s[kf][r] * 0.125f);
        lsum[r] += p;
        const int row = w * 16 + lq * 4 + r;
        Ps[row * 72 + ((kf * 16 + lr) ^ Sw)] = (bf16)p;
      }
    }

    bf16x8 ap[2];
#pragma unroll
    for (int ks = 0; ks < 2; ks++)
      ap[ks] = *(const bf16x8*)&Ps[(w * 16 + lr) * 72 + ((ks * 32 + lq * 8) ^ Sr)];
#pragma unroll
    for (int hf = 0; hf < 4; hf++) {
      const int vrow = hf * 16 + lr;
#pragma unroll
      for (int ks = 0; ks < 2; ks++) {
        bf16x8 bv = *(const bf16x8*)&Vt[vrow * 72 + ((ks * 32 + lq * 8) ^ (vrow & 56))];
        o[hf] = __builtin_amdgcn_mfma_f32_16x16x32_bf16(ap[ks], bv, o[hf], 0, 0, 0);
      }
    }
  }

#pragma unroll
  for (int r = 0; r < 4; r++) {
#pragma unroll
    for (int d = 1; d < 16; d <<= 1) lsum[r] += __shfl_xor(lsum[r], d, 64);
  }

#pragma unroll
  for (int r = 0; r < 4; r++) {
    const int rowj = w * 16 + lq * 4 + r;
    if (qt * 64 + rowj < nb) {
      const float inv = 1.0f / lsum[r];
      const size_t row = rowbase + Ts[rowj];
#pragma unroll
      for (int hf = 0; hf < 4; hf++)
        ctx[row * 1024 + hcol + hf * 16 + lr] = (bf16)(o[hf][r] * inv);
    }
  }
}

// ---------------- launch ----------------
extern "C" void kernel_launch(void* const* d_in, const int* in_sizes, int n_in,
                              void* d_out, int out_size, void* d_ws, size_t ws_size,
                              hipStream_t stream) {
  (void)in_sizes; (void)n_in; (void)out_size; (void)ws_size;
  const float* x    = (const float*)d_in[0];
  const float* a_nw = (const float*)d_in[1];
  const float* a_nb = (const float*)d_in[2];
  const float* in_w = (const float*)d_in[3];
  const float* in_b = (const float*)d_in[4];
  const float* o_w  = (const float*)d_in[5];
  const float* o_b  = (const float*)d_in[6];
  const float* f_nw = (const float*)d_in[7];
  const float* f_nb = (const float*)d_in[8];
  const float* w1   = (const float*)d_in[9];
  const float* b1   = (const float*)d_in[10];
  const float* w2   = (const float*)d_in[11];
  const float* b2   = (const float*)d_in[12];
  const float* r_nw = (const float*)d_in[13];
  const float* r_nb = (const float*)d_in[14];
  const float* rw1  = (const float*)d_in[15];
  const float* rb1  = (const float*)d_in[16];
  const float* rw2  = (const float*)d_in[17];
  const float* rb2  = (const float*)d_in[18];

  float* cur    = (float*)d_out;
  float* depths = cur + 8388608;
  float* logits = depths + 8192;

  char* ws = (char*)d_ws;
  bf16* wb_in  = (bf16*)(ws + 0);
  bf16* wb_out = (bf16*)(ws + 6291456);
  bf16* wb_f1  = (bf16*)(ws + 8388608);
  bf16* wb_f2  = (bf16*)(ws + 16777216);
  bf16* r1h    = (bf16*)(ws + 25165824);
  bf16* r1m    = (bf16*)(ws + 27262976);
  bf16* r1l    = (bf16*)(ws + 29360128);
  bf16* Abuf   = (bf16*)(ws + 31457280);
  bf16* Bbuf   = (bf16*)(ws + 48234496);
  bf16* Big    = (bf16*)(ws + 65011712);
  float* Tmp   = (float*)(ws + 132120576);
  bf16* VtG    = (bf16*)(ws + 132120576);   // aliases Tmp: live ranges disjoint
  int*  gate   = (int*)(ws + 165675008);
  // idx/cnt arrays alias the router split-weight buffers (dead after gemm_router)
  int* idx_all  = (int*)(ws + 25165824);    // 6*8192 ints (aliases r1h)
  int* bidx_all = (int*)(ws + 27262976);    // 6*8192 ints (aliases r1m)
  int* cnt_all  = (int*)(ws + 29360128);    // 6 ints      (aliases r1l)
  int* bcnt_all = cnt_all + 16;             // 48 ints

  hipMemcpyAsync(cur, x, (size_t)8388608 * 4, hipMemcpyDeviceToDevice, stream);

  f2b_kernel<<<3072, 256, 0, stream>>>(in_w, wb_in, 3145728);
  f2b_kernel<<<1024, 256, 0, stream>>>(o_w, wb_out, 1048576);
  f2b_kernel<<<4096, 256, 0, stream>>>(w1, wb_f1, 4194304);
  f2b_kernel<<<4096, 256, 0, stream>>>(w2, wb_f2, 4194304);
  split3_kernel<<<1024, 256, 0, stream>>>(rw1, r1h, r1m, r1l, 1048576);

  // ---- router ----
  ln_kernel<3><<<8192, 256, 0, stream>>>(x, r_nw, r_nb, Abuf, Bbuf, Big);
  gemm_router<<<dim3(8, 64), 256, 0, stream>>>(Abuf, Bbuf, Big, r1h, r1m, r1l, Tmp);
  gelu_bias_kernel<<<8192, 256, 0, stream>>>(Tmp, rb1, 8388608);
  router_logits<<<2048, 256, 0, stream>>>(Tmp, rw2, rb2, logits, depths, gate);
  zero_cnt_kernel<<<1, 64, 0, stream>>>(cnt_all, bcnt_all);
  build_idx_kernel<<<48, 256, 0, stream>>>(gate, idx_all, cnt_all, bidx_all, bcnt_all);

  // ---- 6 recursion levels, depth-compacted ----
  for (int level = 1; level <= 6; level++) {
    const int lev = level - 1;
    const int* idxL  = idx_all + lev * 8192;
    const int* cntL  = cnt_all + lev;
    const int* bidxL = bidx_all + lev * 8192;
    const int* bcntL = bcnt_all + lev * 8;

    ln_kernel<1><<<8192, 256, 0, stream>>>(cur, a_nw, a_nb, Abuf, nullptr, nullptr);
    // K,V projection: all rows (frozen tokens still serve as keys/values)
    gemm256<0, 256><<<dim3(8, 32), 512, 0, stream>>>(Abuf, wb_in + 1048576, in_b + 1024,
        nullptr, nullptr, Big, nullptr, nullptr, 2048, 1024, 3072, 1024);
    // Q projection: active rows only, scatter into Big
    gemm256<1, 128><<<dim3(8, 32), 512, 0, stream>>>(Abuf, wb_in, in_b,
        nullptr, nullptr, Big, idxL, cntL, 1024, 1024, 3072, 0);
    vtrans_kernel<<<2048, 256, 0, stream>>>(Big, VtG);
    attn_kernel<<<2048, 256, 0, stream>>>(Big, VtG, Bbuf, bidxL, bcntL);
    // out-proj: gather ctx + residual, compact output
    gemm256<2, 128><<<dim3(8, 32), 512, 0, stream>>>(Bbuf, wb_out, o_b,
        cur, Tmp, nullptr, idxL, cntL, 1024, 1024, 0, 0);
    ln_c_kernel<<<8192, 256, 0, stream>>>(Tmp, f_nw, f_nb, Abuf, cntL);
    gemm256<3, 256><<<dim3(16, 32), 512, 0, stream>>>(Abuf, wb_f1, b1,
        nullptr, nullptr, Big, idxL, cntL, 4096, 1024, 0, 0);
    gemm256<4, 128><<<dim3(8, 32), 512, 0, stream>>>(Big, wb_f2, b2,
        Tmp, cur, nullptr, idxL, cntL, 1024, 4096, 0, 0);
  }
}

// Round 3
// 2297.147 us; speedup vs baseline: 1.1370x; 1.0210x over previous
//
#include <hip/hip_runtime.h>
#include <cstdint>
#include <cstddef>

typedef __bf16 bf16;
typedef bf16 bf16x8 __attribute__((ext_vector_type(8)));
typedef float f32x4 __attribute__((ext_vector_type(4)));

#define GAS __attribute__((address_space(1)))
#define LAS __attribute__((address_space(3)))

__device__ __forceinline__ void async_cp16(const bf16* g, bf16* l) {
  __builtin_amdgcn_global_load_lds((const GAS unsigned int*)g,
                                   (LAS unsigned int*)l, 16, 0, 0);
}

__device__ __forceinline__ float gelu_f(float x) {
  return 0.5f * x * (1.0f + erff(x * 0.70710678118654752440f));
}

// ---------------- weight conversion ----------------
__global__ void __launch_bounds__(256) f2b_kernel(const float* __restrict__ in,
                                                  bf16* __restrict__ out, int n) {
  int i = (blockIdx.x * 256 + threadIdx.x) * 4;
  if (i >= n) return;
  float4 v = *(const float4*)&in[i];
  union { uint2 u; bf16 e[4]; } o;
  o.e[0] = (bf16)v.x; o.e[1] = (bf16)v.y; o.e[2] = (bf16)v.z; o.e[3] = (bf16)v.w;
  *(uint2*)&out[i] = o.u;
}

__global__ void __launch_bounds__(256) split3_kernel(const float* __restrict__ in,
    bf16* __restrict__ oh, bf16* __restrict__ om, bf16* __restrict__ ol, int n) {
  int i = (blockIdx.x * 256 + threadIdx.x) * 4;
  if (i >= n) return;
  float4 v = *(const float4*)&in[i];
  float a[4] = {v.x, v.y, v.z, v.w};
  union { uint2 u; bf16 e[4]; } h, m, l;
#pragma unroll
  for (int j = 0; j < 4; j++) {
    h.e[j] = (bf16)a[j];
    float r = a[j] - (float)h.e[j];
    m.e[j] = (bf16)r;
    l.e[j] = (bf16)(r - (float)m.e[j]);
  }
  *(uint2*)&oh[i] = h.u;
  *(uint2*)&om[i] = m.u;
  *(uint2*)&ol[i] = l.u;
}

// ---------------- layernorm (full M; optional 3-way split) ----------------
template<int SPLIT>
__global__ void __launch_bounds__(256) ln_kernel(const float* __restrict__ X,
    const float* __restrict__ w, const float* __restrict__ b,
    bf16* __restrict__ oh, bf16* __restrict__ om, bf16* __restrict__ ol) {
  const int row = blockIdx.x;
  const int tid = threadIdx.x;
  const float4 xv = *(const float4*)&X[(size_t)row * 1024 + tid * 4];
  float s1 = xv.x + xv.y + xv.z + xv.w;
  float s2 = xv.x * xv.x + xv.y * xv.y + xv.z * xv.z + xv.w * xv.w;
#pragma unroll
  for (int d = 1; d < 64; d <<= 1) {
    s1 += __shfl_xor(s1, d, 64);
    s2 += __shfl_xor(s2, d, 64);
  }
  __shared__ float red[8];
  if ((tid & 63) == 0) { red[tid >> 6] = s1; red[4 + (tid >> 6)] = s2; }
  __syncthreads();
  s1 = red[0] + red[1] + red[2] + red[3];
  s2 = red[4] + red[5] + red[6] + red[7];
  const float mu = s1 * (1.0f / 1024.0f);
  const float var = s2 * (1.0f / 1024.0f) - mu * mu;
  const float rs = rsqrtf(var + 1e-5f);
  const float4 wv = *(const float4*)&w[tid * 4];
  const float4 bv = *(const float4*)&b[tid * 4];
  float y[4] = {(xv.x - mu) * rs * wv.x + bv.x,
                (xv.y - mu) * rs * wv.y + bv.y,
                (xv.z - mu) * rs * wv.z + bv.z,
                (xv.w - mu) * rs * wv.w + bv.w};
  union { uint2 u; bf16 e[4]; } h;
#pragma unroll
  for (int j = 0; j < 4; j++) h.e[j] = (bf16)y[j];
  *(uint2*)&oh[(size_t)row * 1024 + tid * 4] = h.u;
  if (SPLIT == 3) {
    union { uint2 u; bf16 e[4]; } m, l;
#pragma unroll
    for (int j = 0; j < 4; j++) {
      float r = y[j] - (float)h.e[j];
      m.e[j] = (bf16)r;
      l.e[j] = (bf16)(r - (float)m.e[j]);
    }
    *(uint2*)&om[(size_t)row * 1024 + tid * 4] = m.u;
    *(uint2*)&ol[(size_t)row * 1024 + tid * 4] = l.u;
  }
}

// ---------------- layernorm on compacted rows, zero-fill to 128-pad ----------------
__global__ void __launch_bounds__(256) ln_c_kernel(const float* __restrict__ X,
    const float* __restrict__ w, const float* __restrict__ b,
    bf16* __restrict__ oh, const int* __restrict__ cnt_ptr) {
  const int row = blockIdx.x;
  const int cnt = *cnt_ptr;
  const int pad = (cnt + 127) & ~127;
  if (row >= pad) return;
  const int tid = threadIdx.x;
  if (row >= cnt) {
    *(uint2*)&oh[(size_t)row * 1024 + tid * 4] = make_uint2(0, 0);
    return;
  }
  const float4 xv = *(const float4*)&X[(size_t)row * 1024 + tid * 4];
  float s1 = xv.x + xv.y + xv.z + xv.w;
  float s2 = xv.x * xv.x + xv.y * xv.y + xv.z * xv.z + xv.w * xv.w;
#pragma unroll
  for (int d = 1; d < 64; d <<= 1) {
    s1 += __shfl_xor(s1, d, 64);
    s2 += __shfl_xor(s2, d, 64);
  }
  __shared__ float red[8];
  if ((tid & 63) == 0) { red[tid >> 6] = s1; red[4 + (tid >> 6)] = s2; }
  __syncthreads();
  s1 = red[0] + red[1] + red[2] + red[3];
  s2 = red[4] + red[5] + red[6] + red[7];
  const float mu = s1 * (1.0f / 1024.0f);
  const float var = s2 * (1.0f / 1024.0f) - mu * mu;
  const float rs = rsqrtf(var + 1e-5f);
  const float4 wv = *(const float4*)&w[tid * 4];
  const float4 bv = *(const float4*)&b[tid * 4];
  union { uint2 u; bf16 e[4]; } h;
  h.e[0] = (bf16)((xv.x - mu) * rs * wv.x + bv.x);
  h.e[1] = (bf16)((xv.y - mu) * rs * wv.y + bv.y);
  h.e[2] = (bf16)((xv.z - mu) * rs * wv.z + bv.z);
  h.e[3] = (bf16)((xv.w - mu) * rs * wv.w + bv.w);
  *(uint2*)&oh[(size_t)row * 1024 + tid * 4] = h.u;
}

// ---------------- depth-compaction index build ----------------
__global__ void zero_cnt_kernel(int* cnt_all, int* bcnt_all) {
  if (threadIdx.x < 6) cnt_all[threadIdx.x] = 0;
  if (threadIdx.x < 48) bcnt_all[threadIdx.x] = 0;
}

__global__ void __launch_bounds__(256) build_idx_kernel(
    const int* __restrict__ gate, int* __restrict__ idx_all,
    int* __restrict__ cnt_all, int* __restrict__ bidx_all,
    int* __restrict__ bcnt_all) {
  const int lev = blockIdx.x >> 3;   // 0..5
  const int b   = blockIdx.x & 7;
  const int level = lev + 1;
  int* idx  = idx_all + lev * 8192;
  int* bidx = bidx_all + lev * 8192 + b * 1024;
  for (int t = threadIdx.x; t < 1024; t += 256) {
    const int row = b * 1024 + t;
    if (gate[row] >= level) {
      int p = atomicAdd(&bcnt_all[lev * 8 + b], 1);
      bidx[p] = t;
      int q = atomicAdd(&cnt_all[lev], 1);
      idx[q] = row;
    }
  }
}

// XCD-aware block remap (128-tile version, used by gemm_router).
__device__ __forceinline__ void swizzle_mn(int gx, int& m0, int& n0) {
  const int id = blockIdx.y * gx + blockIdx.x;
  const int k8 = id & 7, t = id >> 3;
  n0 = (t % gx) * 128;
  m0 = ((t / gx) * 8 + k8) * 128;
}

// ================= 256-row-tile 8-wave 4-phase pipelined NT GEMM =================
// v3: overlap inside the phase.
//  - ONE barrier per phase (phase-open). Safety: every phase's consumed ds_reads
//    are lgkm-drained before its MFMAs issue, so arrival at the next barrier
//    implies all reads of the current buffers retired; stageB(t+2) at p2 then
//    cannot overwrite B(t) before it is fully read. Pending prefetch reads at a
//    barrier touch only the A-region of buffer bf, which no in-flight stage
//    writes (A(t+1)->bf^1, B(t+2)->B-region).
//  - A-fragment prefetch one phase ahead (same tile, same buffer: race-free),
//    issued before the MFMA cluster so read latency hides under MFMA.
//  - ks-outer MFMA order: consecutive MFMAs hit different accumulators (8 apart
//    before reuse); per-accumulator accumulation order unchanged (bitwise same).
//  - counted vmcnt once per tile at p3 (never 0 in steady state).
template<int MODE, int BN>
__global__ void __launch_bounds__(512, 2) gemm256(
    const bf16* __restrict__ A, const bf16* __restrict__ B,
    const float* __restrict__ bias, const float* __restrict__ Res,
    float* __restrict__ C32, bf16* __restrict__ Cb,
    const int* __restrict__ idx, const int* __restrict__ cnt_ptr,
    int N, int K, int ldc, int coff) {
  __shared__ bf16 lds[65536];   // 128 KiB: A halves [0,32768), B halves [32768,65536)
  const int tid = threadIdx.x;
  const int w = tid >> 6, lane = tid & 63;
  const int lr = lane & 15, lq = lane >> 4;
  constexpr int MI  = (BN == 256) ? 8 : 4;   // A frags per wave
  constexpr int MPH = (BN == 256) ? 2 : 1;   // A frags per phase
  constexpr int NBH = (BN == 256) ? 2 : 1;   // B half-tiles
  const int wr = (BN == 256) ? (w >> 2) : (w >> 1);
  const int wc = (BN == 256) ? (w & 3) : (w & 1);

  // XCD-aware tile coords (grid.x * grid.y is a multiple of 8 in all call sites)
  const int gx = gridDim.x;
  const int id = blockIdx.y * gx + blockIdx.x;
  const int k8 = id & 7, tt = id >> 3;
  const int n0 = (tt % gx) * BN;
  const int m0 = ((tt / gx) * 8 + k8) * 256;

  int cnt = 0x7fffffff;
  if (MODE != 0) {
    cnt = *cnt_ptr;
    if (m0 >= cnt) return;
  }

  const int NT = K >> 6;

  // ---- staging source pointers (per-thread, swizzled k-chunk) ----
  const int srow  = tid >> 3;                       // 0..63
  const int skoff = ((tid & 7) ^ (srow & 7)) * 8;   // LDS[row][slot]=G[row][slot^(row&7)]
  const bf16* gA[4];
#pragma unroll
  for (int h = 0; h < 2; h++)
#pragma unroll
    for (int j = 0; j < 2; j++) {
      const int i = m0 + h * 128 + j * 64 + srow;
      size_t ar;
      if (MODE == 1 || MODE == 2) ar = (size_t)idx[i < cnt ? i : 0];
      else ar = (size_t)i;
      gA[h * 2 + j] = A + ar * (size_t)K + skoff;
    }
  const bf16* gB[4];
#pragma unroll
  for (int h = 0; h < NBH; h++)
#pragma unroll
    for (int j = 0; j < 2; j++)
      gB[h * 2 + j] = B + (size_t)(n0 + h * 128 + j * 64 + srow) * K + skoff;

  auto stageA = [&](int bf, int h, int t) {
#pragma unroll
    for (int j = 0; j < 2; j++)
      async_cp16(gA[h * 2 + j] + (size_t)t * 64,
                 &lds[(bf * 2 + h) * 8192 + (j * 64 + w * 8) * 64]);
  };
  auto stageB = [&](int bf, int h, int t) {
#pragma unroll
    for (int j = 0; j < 2; j++)
      async_cp16(gB[h * 2 + j] + (size_t)t * 64,
                 &lds[32768 + (bf * 2 + h) * 8192 + (j * 64 + w * 8) * 64]);
  };

  // ---- fragment read helpers (swizzled) ----
  const int ah  = (BN == 256) ? wr : (wr >> 1);          // A half for this wave
  const int arb = (BN == 256) ? 0 : ((wr & 1) * 64);     // row base within half
  const int bh  = (BN == 256) ? (wc >> 1) : 0;
  const int brb = (BN == 256) ? ((wc & 1) * 64) : (wc * 64);
  const int swz = (lr & 7);
  auto rdA = [&](int bf, int mi, int ks) {
    return *(const bf16x8*)&lds[(bf * 2 + ah) * 8192 + (arb + mi * 16 + lr) * 64
                                + (((ks * 4 + lq) ^ swz) * 8)];
  };
  auto rdB = [&](int bf, int ni, int ks) {
    return *(const bf16x8*)&lds[32768 + (bf * 2 + bh) * 8192
                                + (brb + ni * 16 + lr) * 64
                                + (((ks * 4 + lq) ^ swz) * 8)];
  };

  f32x4 acc[MI][4] = {};
  bf16x8 bq[4][2];
  bf16x8 af[2][2 * MPH];

  // ---- prologue: tile0 fully + B(1); A(1) is staged inside t=0 ----
  stageA(0, 0, 0); stageA(0, 1, 0);
  stageB(0, 0, 0);
  if (BN == 256) stageB(0, 1, 0);
  stageB(1, 0, 1);
  if (BN == 256) stageB(1, 1, 1);
  asm volatile("s_waitcnt vmcnt(0)" ::: "memory");

  for (int t = 0; t < NT; ++t) {
    const int bf = t & 1;
#pragma unroll
    for (int p = 0; p < 4; ++p) {
      __builtin_amdgcn_s_barrier();
      if (p == 0) {
        // exposed reads: this phase's A frags + all B frags for the tile
#pragma unroll
        for (int m = 0; m < MPH; m++)
#pragma unroll
          for (int ks = 0; ks < 2; ks++)
            af[0][m * 2 + ks] = rdA(bf, m, ks);
#pragma unroll
        for (int ni = 0; ni < 4; ni++)
#pragma unroll
          for (int ks = 0; ks < 2; ks++)
            bq[ni][ks] = rdB(bf, ni, ks);
      }
      // one half-tile stage per phase
      if (p == 0)      { if (t + 1 < NT) stageA(bf ^ 1, 0, t + 1); }
      else if (p == 1) { if (t + 1 < NT) stageA(bf ^ 1, 1, t + 1); }
      else if (p == 2) { if (t + 2 < NT) stageB(bf, 0, t + 2); }
      else if (BN == 256) { if (t + 2 < NT) stageB(bf, 1, t + 2); }
      // prefetch next phase's A frags (same tile, same buffer: race-free) —
      // their latency hides under this phase's MFMA cluster.
      if (p < 3) {
#pragma unroll
        for (int m = 0; m < MPH; m++)
#pragma unroll
          for (int ks = 0; ks < 2; ks++)
            af[(p + 1) & 1][m * 2 + ks] = rdA(bf, (p + 1) * MPH + m, ks);
      }
      __builtin_amdgcn_s_setprio(1);
#pragma unroll
      for (int ks = 0; ks < 2; ks++)
#pragma unroll
        for (int m = 0; m < MPH; m++) {
          const int mi = p * MPH + m;
#pragma unroll
          for (int ni = 0; ni < 4; ni++)
            acc[mi][ni] = __builtin_amdgcn_mfma_f32_16x16x32_bf16(
                af[p & 1][m * 2 + ks], bq[ni][ks], acc[mi][ni], 0, 0, 0);
        }
      __builtin_amdgcn_s_setprio(0);
      if (p == 3) {
        if (t + 2 < NT) {
          if constexpr (BN == 256) asm volatile("s_waitcnt vmcnt(4)" ::: "memory");
          else                     asm volatile("s_waitcnt vmcnt(2)" ::: "memory");
        } else {
          asm volatile("s_waitcnt vmcnt(0)" ::: "memory");
        }
      }
    }
  }

  // ---- epilogue (same semantics as old gemm_nt) ----
  const int rw = m0 + ((BN == 256) ? wr * 128 : wr * 64);
#pragma unroll
  for (int mi = 0; mi < MI; mi++) {
    const int rbase = rw + mi * 16 + lq * 4;
    int orig[4];
#pragma unroll
    for (int r = 0; r < 4; r++) {
      const int i = rbase + r;
      if (MODE == 1 || MODE == 2 || MODE == 4) orig[r] = (i < cnt) ? idx[i] : -1;
      else orig[r] = i;
    }
#pragma unroll
    for (int ni = 0; ni < 4; ni++) {
      const int c = n0 + wc * 64 + ni * 16 + lr;
      const float bv = bias[c];
#pragma unroll
      for (int r = 0; r < 4; r++) {
        const float v = acc[mi][ni][r] + bv;
        const int i = rbase + r;
        if (MODE == 0) {
          Cb[(size_t)i * ldc + coff + c] = (bf16)v;
        } else if (MODE == 1) {
          if (orig[r] >= 0) Cb[(size_t)orig[r] * ldc + c] = (bf16)v;
        } else if (MODE == 2) {
          const float rv = (orig[r] >= 0) ? Res[(size_t)orig[r] * N + c] : 0.0f;
          C32[(size_t)i * N + c] = rv + v;
        } else if (MODE == 3) {
          Cb[(size_t)i * N + c] = (bf16)gelu_f(v);
        } else {
          if (orig[r] >= 0)
            C32[(size_t)orig[r] * N + c] = Res[(size_t)i * N + c] + v;
        }
      }
    }
  }
}

// ---------------- fused 6-product split-bf16 router GEMM ----------------
__global__ void __launch_bounds__(256) gemm_router(
    const bf16* __restrict__ Ah, const bf16* __restrict__ Am, const bf16* __restrict__ Al,
    const bf16* __restrict__ Bh, const bf16* __restrict__ Bm, const bf16* __restrict__ Bl,
    float* __restrict__ C32) {
  __shared__ bf16 As[3][128 * 32];
  __shared__ bf16 Bs[3][128 * 32];
  const int tid = threadIdx.x;
  const int w = tid >> 6, lane = tid & 63;
  const int lr = lane & 15, lq = lane >> 4;
  int m0, n0;
  swizzle_mn(gridDim.x, m0, n0);
  const int wm = (w >> 1) * 64, wn = (w & 1) * 64;
  const int K = 1024;

  f32x4 acc[4][4] = {};

  const size_t aoff = (size_t)(m0 + (tid >> 2)) * K + (tid & 3) * 8;
  const size_t boff = (size_t)(n0 + (tid >> 2)) * K + (tid & 3) * 8;
  const bf16* gA[3] = {Ah + aoff, Am + aoff, Al + aoff};
  const bf16* gB[3] = {Bh + boff, Bm + boff, Bl + boff};
  const int lo = w * 512;
  const size_t step64 = (size_t)64 * K;

  const int cA[6] = {0, 0, 1, 1, 0, 2};
  const int cB[6] = {0, 1, 0, 1, 2, 0};

  for (int k0 = 0; k0 < K; k0 += 32) {
    __syncthreads();
#pragma unroll
    for (int j = 0; j < 3; j++) {
      async_cp16(gA[j] + k0, As[j] + lo);
      async_cp16(gA[j] + step64 + k0, As[j] + lo + 2048);
      async_cp16(gB[j] + k0, Bs[j] + lo);
      async_cp16(gB[j] + step64 + k0, Bs[j] + lo + 2048);
    }
    __syncthreads();
#pragma unroll
    for (int c = 0; c < 6; c++) {
      bf16x8 af[4], bfr[4];
#pragma unroll
      for (int i = 0; i < 4; i++)
        af[i] = *(const bf16x8*)&As[cA[c]][(wm + i * 16 + lr) * 32 + lq * 8];
#pragma unroll
      for (int i = 0; i < 4; i++)
        bfr[i] = *(const bf16x8*)&Bs[cB[c]][(wn + i * 16 + lr) * 32 + lq * 8];
#pragma unroll
      for (int mi = 0; mi < 4; mi++)
#pragma unroll
        for (int ni = 0; ni < 4; ni++)
          acc[mi][ni] = __builtin_amdgcn_mfma_f32_16x16x32_bf16(
              af[mi], bfr[ni], acc[mi][ni], 0, 0, 0);
    }
  }

#pragma unroll
  for (int mi = 0; mi < 4; mi++) {
    const int rbase = m0 + wm + mi * 16 + lq * 4;
#pragma unroll
    for (int ni = 0; ni < 4; ni++) {
      const int c = n0 + wn + ni * 16 + lr;
#pragma unroll
      for (int r = 0; r < 4; r++)
        C32[(size_t)(rbase + r) * 1024 + c] = acc[mi][ni][r];
    }
  }
}

// ---------------- router tail ----------------
__global__ void __launch_bounds__(256) gelu_bias_kernel(float* __restrict__ t,
    const float* __restrict__ bias, int n) {
  int i = (blockIdx.x * 256 + threadIdx.x) * 4;
  if (i >= n) return;
  float4 v = *(const float4*)&t[i];
  float4 bb = *(const float4*)&bias[i & 1023];
  v.x = gelu_f(v.x + bb.x);
  v.y = gelu_f(v.y + bb.y);
  v.z = gelu_f(v.z + bb.z);
  v.w = gelu_f(v.w + bb.w);
  *(float4*)&t[i] = v;
}

__global__ void __launch_bounds__(256) router_logits(const float* __restrict__ h,
    const float* __restrict__ w2, const float* __restrict__ b2,
    float* __restrict__ logits_out, float* __restrict__ depths_out,
    int* __restrict__ gate) {
  const int row = blockIdx.x * 4 + (threadIdx.x >> 6);
  const int lane = threadIdx.x & 63;
  const float* hr = h + (size_t)row * 1024;
  float part[6] = {0, 0, 0, 0, 0, 0};
  for (int kc = lane; kc < 256; kc += 64) {
    float4 hv = *(const float4*)&hr[kc * 4];
#pragma unroll
    for (int j = 0; j < 6; j++) {
      float4 wv = *(const float4*)&w2[j * 1024 + kc * 4];
      part[j] += hv.x * wv.x + hv.y * wv.y + hv.z * wv.z + hv.w * wv.w;
    }
  }
#pragma unroll
  for (int j = 0; j < 6; j++)
#pragma unroll
    for (int d = 1; d < 64; d <<= 1) part[j] += __shfl_xor(part[j], d, 64);
  if (lane == 0) {
    float best = -1e30f;
    int bi = 0;
#pragma unroll
    for (int j = 0; j < 6; j++) {
      const float v = part[j] + b2[j];
      logits_out[(size_t)row * 6 + j] = v;
      if (v > best) { best = v; bi = j; }
    }
    depths_out[row] = (float)(bi + 1);
    gate[row] = bi + 1;
  }
}

// ---------------- V transpose ----------------
__global__ void __launch_bounds__(256) vtrans_kernel(const bf16* __restrict__ qkv,
                                                     bf16* __restrict__ vt) {
  __shared__ bf16 T[64 * 64];
  const int tid = threadIdx.x;
  const int tb = blockIdx.x & 15, bh = blockIdx.x >> 4;
  const int b = bh >> 4, h = bh & 15;
#pragma unroll
  for (int i = 0; i < 2; i++) {
    const int c = tid + i * 256;
    const int tok = c >> 3, hd8 = (c & 7) * 8;
    uint4 v = *(const uint4*)&qkv[((size_t)b * 1024 + tb * 64 + tok) * 3072 + 2048 + h * 64 + hd8];
    *(uint4*)&T[tok * 64 + (hd8 ^ ((tok & 7) << 3))] = v;
  }
  __syncthreads();
#pragma unroll
  for (int i = 0; i < 2; i++) {
    const int c = tid + i * 256;
    const int hd = c >> 3, t8 = (c & 7) * 8;
    union { uint4 u; bf16 e[8]; } o;
#pragma unroll
    for (int j = 0; j < 8; j++)
      o.e[j] = T[(t8 + j) * 64 + (hd ^ (j << 3))];
    *(uint4*)&vt[((size_t)bh * 64 + hd) * 1024 + tb * 64 + t8] = o.u;
  }
}

// ---------------- flash attention, compacted q-rows ----------------
__global__ void __launch_bounds__(256) attn_kernel(const bf16* __restrict__ qkv,
    const bf16* __restrict__ vtg, bf16* __restrict__ ctx,
    const int* __restrict__ bidx, const int* __restrict__ bcnt) {
  __shared__ bf16 Qs[64 * 72];
  __shared__ bf16 Ks[64 * 72];
  __shared__ bf16 Vt[64 * 72];
  __shared__ bf16 Ps[64 * 72];
  __shared__ int Ts[64];
  const int tid = threadIdx.x;
  const int w = tid >> 6, lane = tid & 63;
  const int lr = lane & 15, lq = lane >> 4;
  const int blk = blockIdx.x;
  const int bh = (blk & 7) | ((blk >> 7) << 3);
  const int qt = (blk >> 3) & 15;
  const int b = bh >> 4, h = bh & 15;
  const int nb = bcnt[b];
  if (qt * 64 >= nb) return;
  const size_t rowbase = (size_t)b * 1024;
  const int hcol = h * 64;
  const size_t vbase = (size_t)bh * 65536;

  if (tid < 64) {
    const int j = qt * 64 + tid;
    Ts[tid] = (j < nb) ? bidx[b * 1024 + j] : bidx[b * 1024 + qt * 64];
  }
  __syncthreads();

#pragma unroll
  for (int i = 0; i < 2; i++) {
    const int c = tid + i * 256;
    const int r = c >> 3, k8 = (c & 7) * 8;
    uint4 v = *(const uint4*)&qkv[(rowbase + Ts[r]) * 3072 + hcol + k8];
    *(uint4*)&Qs[r * 72 + k8] = v;
  }
  __syncthreads();
  bf16x8 aq[2];
#pragma unroll
  for (int hs = 0; hs < 2; hs++)
    aq[hs] = *(const bf16x8*)&Qs[(w * 16 + lr) * 72 + hs * 32 + lq * 8];

  float lsum[4] = {0.0f, 0.0f, 0.0f, 0.0f};
  f32x4 o[4];
#pragma unroll
  for (int i = 0; i < 4; i++) o[i] = (f32x4)0.0f;

  const int Sw = ((w * 4 + lq) & 7) << 3;
  const int Sr = ((w * 4 + (lr >> 2)) & 7) << 3;

  for (int kb = 0; kb < 16; kb++) {
    __syncthreads();
#pragma unroll
    for (int i = 0; i < 2; i++) {
      const int c = tid + i * 256;
      const int r = c >> 3, k8 = (c & 7) * 8;
      uint4 v = *(const uint4*)&qkv[(rowbase + kb * 64 + r) * 3072 + 1024 + hcol + k8];
      *(uint4*)&Ks[r * 72 + k8] = v;
    }
#pragma unroll
    for (int i = 0; i < 2; i++) {
      const int c = tid + i * 256;
      const int hd = c >> 3, t8 = (c & 7) * 8;
      uint4 v = *(const uint4*)&vtg[vbase + (size_t)hd * 1024 + kb * 64 + t8];
      *(uint4*)&Vt[hd * 72 + (t8 ^ (hd & 56))] = v;
    }
    __syncthreads();

    // QK^T: read all K frags upfront, hs-outer so consecutive MFMAs hit
    // different accumulators (per-acc order unchanged: hs=0 then hs=1).
    bf16x8 bk[4][2];
#pragma unroll
    for (int kf = 0; kf < 4; kf++)
#pragma unroll
      for (int hs = 0; hs < 2; hs++)
        bk[kf][hs] = *(const bf16x8*)&Ks[(kf * 16 + lr) * 72 + hs * 32 + lq * 8];
    f32x4 s[4];
#pragma unroll
    for (int kf = 0; kf < 4; kf++) s[kf] = (f32x4)0.0f;
#pragma unroll
    for (int hs = 0; hs < 2; hs++)
#pragma unroll
      for (int kf = 0; kf < 4; kf++)
        s[kf] = __builtin_amdgcn_mfma_f32_16x16x32_bf16(aq[hs], bk[kf][hs], s[kf], 0, 0, 0);

#pragma unroll
    for (int kf = 0; kf < 4; kf++) {
#pragma unroll
      for (int r = 0; r < 4; r++) {
        const float p = __expf(s[kf][r] * 0.125f);
        lsum[r] += p;
        const int row = w * 16 + lq * 4 + r;
        Ps[row * 72 + ((kf * 16 + lr) ^ Sw)] = (bf16)p;
      }
    }

    bf16x8 ap[2];
#pragma unroll
    for (int ks = 0; ks < 2; ks++)
      ap[ks] = *(const bf16x8*)&Ps[(w * 16 + lr) * 72 + ((ks * 32 + lq * 8) ^ Sr)];
    // PV: read all V frags upfront, ks-outer (per-acc order unchanged).
    bf16x8 bv[4][2];
#pragma unroll
    for (int hf = 0; hf < 4; hf++) {
      const int vrow = hf * 16 + lr;
#pragma unroll
      for (int ks = 0; ks < 2; ks++)
        bv[hf][ks] = *(const bf16x8*)&Vt[vrow * 72 + ((ks * 32 + lq * 8) ^ (vrow & 56))];
    }
#pragma unroll
    for (int ks = 0; ks < 2; ks++)
#pragma unroll
      for (int hf = 0; hf < 4; hf++)
        o[hf] = __builtin_amdgcn_mfma_f32_16x16x32_bf16(ap[ks], bv[hf][ks], o[hf], 0, 0, 0);
  }

#pragma unroll
  for (int r = 0; r < 4; r++) {
#pragma unroll
    for (int d = 1; d < 16; d <<= 1) lsum[r] += __shfl_xor(lsum[r], d, 64);
  }

#pragma unroll
  for (int r = 0; r < 4; r++) {
    const int rowj = w * 16 + lq * 4 + r;
    if (qt * 64 + rowj < nb) {
      const float inv = 1.0f / lsum[r];
      const size_t row = rowbase + Ts[rowj];
#pragma unroll
      for (int hf = 0; hf < 4; hf++)
        ctx[row * 1024 + hcol + hf * 16 + lr] = (bf16)(o[hf][r] * inv);
    }
  }
}

// ---------------- launch ----------------
extern "C" void kernel_launch(void* const* d_in, const int* in_sizes, int n_in,
                              void* d_out, int out_size, void* d_ws, size_t ws_size,
                              hipStream_t stream) {
  (void)in_sizes; (void)n_in; (void)out_size; (void)ws_size;
  const float* x    = (const float*)d_in[0];
  const float* a_nw = (const float*)d_in[1];
  const float* a_nb = (const float*)d_in[2];
  const float* in_w = (const float*)d_in[3];
  const float* in_b = (const float*)d_in[4];
  const float* o_w  = (const float*)d_in[5];
  const float* o_b  = (const float*)d_in[6];
  const float* f_nw = (const float*)d_in[7];
  const float* f_nb = (const float*)d_in[8];
  const float* w1   = (const float*)d_in[9];
  const float* b1   = (const float*)d_in[10];
  const float* w2   = (const float*)d_in[11];
  const float* b2   = (const float*)d_in[12];
  const float* r_nw = (const float*)d_in[13];
  const float* r_nb = (const float*)d_in[14];
  const float* rw1  = (const float*)d_in[15];
  const float* rb1  = (const float*)d_in[16];
  const float* rw2  = (const float*)d_in[17];
  const float* rb2  = (const float*)d_in[18];

  float* cur    = (float*)d_out;
  float* depths = cur + 8388608;
  float* logits = depths + 8192;

  char* ws = (char*)d_ws;
  bf16* wb_in  = (bf16*)(ws + 0);
  bf16* wb_out = (bf16*)(ws + 6291456);
  bf16* wb_f1  = (bf16*)(ws + 8388608);
  bf16* wb_f2  = (bf16*)(ws + 16777216);
  bf16* r1h    = (bf16*)(ws + 25165824);
  bf16* r1m    = (bf16*)(ws + 27262976);
  bf16* r1l    = (bf16*)(ws + 29360128);
  bf16* Abuf   = (bf16*)(ws + 31457280);
  bf16* Bbuf   = (bf16*)(ws + 48234496);
  bf16* Big    = (bf16*)(ws + 65011712);
  float* Tmp   = (float*)(ws + 132120576);
  bf16* VtG    = (bf16*)(ws + 132120576);   // aliases Tmp: live ranges disjoint
  int*  gate   = (int*)(ws + 165675008);
  // idx/cnt arrays alias the router split-weight buffers (dead after gemm_router)
  int* idx_all  = (int*)(ws + 25165824);    // 6*8192 ints (aliases r1h)
  int* bidx_all = (int*)(ws + 27262976);    // 6*8192 ints (aliases r1m)
  int* cnt_all  = (int*)(ws + 29360128);    // 6 ints      (aliases r1l)
  int* bcnt_all = cnt_all + 16;             // 48 ints

  hipMemcpyAsync(cur, x, (size_t)8388608 * 4, hipMemcpyDeviceToDevice, stream);

  f2b_kernel<<<3072, 256, 0, stream>>>(in_w, wb_in, 3145728);
  f2b_kernel<<<1024, 256, 0, stream>>>(o_w, wb_out, 1048576);
  f2b_kernel<<<4096, 256, 0, stream>>>(w1, wb_f1, 4194304);
  f2b_kernel<<<4096, 256, 0, stream>>>(w2, wb_f2, 4194304);
  split3_kernel<<<1024, 256, 0, stream>>>(rw1, r1h, r1m, r1l, 1048576);

  // ---- router ----
  ln_kernel<3><<<8192, 256, 0, stream>>>(x, r_nw, r_nb, Abuf, Bbuf, Big);
  gemm_router<<<dim3(8, 64), 256, 0, stream>>>(Abuf, Bbuf, Big, r1h, r1m, r1l, Tmp);
  gelu_bias_kernel<<<8192, 256, 0, stream>>>(Tmp, rb1, 8388608);
  router_logits<<<2048, 256, 0, stream>>>(Tmp, rw2, rb2, logits, depths, gate);
  zero_cnt_kernel<<<1, 64, 0, stream>>>(cnt_all, bcnt_all);
  build_idx_kernel<<<48, 256, 0, stream>>>(gate, idx_all, cnt_all, bidx_all, bcnt_all);

  // ---- 6 recursion levels, depth-compacted ----
  for (int level = 1; level <= 6; level++) {
    const int lev = level - 1;
    const int* idxL  = idx_all + lev * 8192;
    const int* cntL  = cnt_all + lev;
    const int* bidxL = bidx_all + lev * 8192;
    const int* bcntL = bcnt_all + lev * 8;

    ln_kernel<1><<<8192, 256, 0, stream>>>(cur, a_nw, a_nb, Abuf, nullptr, nullptr);
    // K,V projection: all rows (frozen tokens still serve as keys/values)
    gemm256<0, 256><<<dim3(8, 32), 512, 0, stream>>>(Abuf, wb_in + 1048576, in_b + 1024,
        nullptr, nullptr, Big, nullptr, nullptr, 2048, 1024, 3072, 1024);
    // Q projection: active rows only, scatter into Big
    gemm256<1, 128><<<dim3(8, 32), 512, 0, stream>>>(Abuf, wb_in, in_b,
        nullptr, nullptr, Big, idxL, cntL, 1024, 1024, 3072, 0);
    vtrans_kernel<<<2048, 256, 0, stream>>>(Big, VtG);
    attn_kernel<<<2048, 256, 0, stream>>>(Big, VtG, Bbuf, bidxL, bcntL);
    // out-proj: gather ctx + residual, compact output
    gemm256<2, 128><<<dim3(8, 32), 512, 0, stream>>>(Bbuf, wb_out, o_b,
        cur, Tmp, nullptr, idxL, cntL, 1024, 1024, 0, 0);
    ln_c_kernel<<<8192, 256, 0, stream>>>(Tmp, f_nw, f_nb, Abuf, cntL);
    gemm256<3, 256><<<dim3(16, 32), 512, 0, stream>>>(Abuf, wb_f1, b1,
        nullptr, nullptr, Big, idxL, cntL, 4096, 1024, 0, 0);
    gemm256<4, 128><<<dim3(8, 32), 512, 0, stream>>>(Big, wb_f2, b2,
        Tmp, cur, nullptr, idxL, cntL, 1024, 4096, 0, 0);
  }
}